// Round 15
// baseline (880.167 us; speedup 1.0000x reference)
//
#include <hip/hip_runtime.h>
#include <hip/hip_bf16.h>

typedef unsigned short u16;
typedef __bf16 bf16x8 __attribute__((ext_vector_type(8)));   // MFMA A/B operand (4 VGPRs)
typedef float  f32x4  __attribute__((ext_vector_type(4)));   // MFMA C/D operand
typedef u16    u16x8  __attribute__((ext_vector_type(8)));

#define HID   96
#define LDP   104          // padded LDS row stride for activation slices
#define MROWS 93312        // B*N*D
#define BN    10368        // B*N
#define GRID_TILE 1458     // MROWS/64
#define FUSE_GRID 2916     // MROWS/32 (2 tiles of 16 rows per block)
#define SGX   100          // f32 LDS stride gate exchange: 4*100 ≡ 16 mod 32 → 2-way (free)
#define PST   97           // padded f32 stride for prep staging (kills 32-way conflicts)
#define TBUF  1664         // u16 elems per 16-row tail buffer (16*LDP)
#define FST   520          // padded u16 frag stride in k_msg LDS (f-step of 3 → bank+12)

// B-fragment-ordered weights: 20 chunks x 18 frags x 512 elems (1KB frags)
// chunk: 0 cr1, 1 cr2, 2 crF=crW2@W1b, 3 dr1, 4 dr2, 5 drF=drW2@W1c,
//        8 gm2a, 10-11 rW12, 12-15 Wf=W2b@Wih^T (gates i,f,g,o), 16-19 Whh
#define FCH 9216           // elems per chunk (18*512)

#define MFMA(a,b,c) __builtin_amdgcn_mfma_f32_16x16x32_bf16((a),(b),(c),0,0,0)

__device__ __forceinline__ float bf2f(u16 x){
  union { float f; unsigned u; } v; v.u = ((unsigned)x) << 16; return v.f;
}
// native cast -> v_cvt_pk_bf16_f32 (RNE, 1 instr / 2 values when paired)
__device__ __forceinline__ u16 f2bf(float f){
  union { __bf16 b; u16 u; } v; v.b = (__bf16)f; return v.u;
}
__device__ __forceinline__ float frcp(float x){ return __builtin_amdgcn_rcpf(x); }
__device__ __forceinline__ float sigf(float x){ return frcp(1.f + __expf(-x)); }
__device__ __forceinline__ float tanhf_(float x){
  float xx = fminf(fmaxf(x, -15.f), 15.f);
  float e = __expf(-2.f * xx);
  return (1.f - e) * frcp(1.f + e);
}
// in-wave LDS write->read ordering (wave-private slices only)
__device__ __forceinline__ void lds_fence(){
  asm volatile("s_waitcnt lgkmcnt(0)" ::: "memory");
}

// ---- fragment loaders -------------------------------------------------------
struct Frags { bf16x8 a0, a1, a2; };

__device__ __forceinline__ Frags load_afrags_g(const u16* __restrict__ A, size_t row0, int lane){
  int t16 = lane & 15, q = lane >> 4;
  const u16* p = A + (row0 + (size_t)t16) * 96 + q * 8;
  Frags f;
  f.a0 = *reinterpret_cast<const bf16x8*>(p);
  f.a1 = *reinterpret_cast<const bf16x8*>(p + 32);
  f.a2 = *reinterpret_cast<const bf16x8*>(p + 64);
  return f;
}
__device__ __forceinline__ Frags load_afrags_s(const u16* sA, int row0, int lane){
  int t16 = lane & 15, q = lane >> 4;
  const u16* p = sA + (row0 + t16) * LDP + q * 8;
  Frags f;
  f.a0 = *reinterpret_cast<const bf16x8*>(p);
  f.a1 = *reinterpret_cast<const bf16x8*>(p + 32);
  f.a2 = *reinterpret_cast<const bf16x8*>(p + 64);
  return f;
}

// ---- one 16x96 layer, weights as global B-frags (L1/L2-resident) ------------
__device__ __forceinline__ void layer_g(Frags f, const u16* __restrict__ wb,
    const float* __restrict__ bias, u16* dst, int dstStride, size_t rowBase,
    bool relu, int lane)
{
  int t16 = lane & 15, q = lane >> 4;
  #pragma unroll
  for (int nt = 0; nt < 6; nt++){
    float b = bias ? bias[nt * 16 + t16] : 0.f;
    f32x4 acc = {b, b, b, b};
    const u16* wp = wb + nt * 1536 + lane * 8;
    acc = MFMA(f.a0, *reinterpret_cast<const bf16x8*>(wp),        acc);
    acc = MFMA(f.a1, *reinterpret_cast<const bf16x8*>(wp + 512),  acc);
    acc = MFMA(f.a2, *reinterpret_cast<const bf16x8*>(wp + 1024), acc);
    #pragma unroll
    for (int j = 0; j < 4; j++){
      float v = acc[j];
      if (relu) v = fmaxf(v, 0.f);
      dst[(rowBase + q * 4 + j) * (size_t)dstStride + nt * 16 + t16] = f2bf(v);
    }
  }
}

// 16-row layer split across 4 waves by col-tile (wave w: nt = w, w+4).
// Cross-wave data: caller must __syncthreads() before reading dst frags.
__device__ __forceinline__ void layer_split(Frags f, const u16* __restrict__ wb,
    const float* __restrict__ bias, u16* dst, bool relu, int lane, int w)
{
  int t16 = lane & 15, q = lane >> 4;
  #pragma unroll
  for (int nt = w; nt < 6; nt += 4){
    float b = bias ? bias[nt * 16 + t16] : 0.f;
    f32x4 acc = {b, b, b, b};
    const u16* wp = wb + nt * 1536 + lane * 8;
    acc = MFMA(f.a0, *reinterpret_cast<const bf16x8*>(wp),        acc);
    acc = MFMA(f.a1, *reinterpret_cast<const bf16x8*>(wp + 512),  acc);
    acc = MFMA(f.a2, *reinterpret_cast<const bf16x8*>(wp + 1024), acc);
    #pragma unroll
    for (int j = 0; j < 4; j++){
      float v = acc[j];
      if (relu) v = fmaxf(v, 0.f);
      dst[(q * 4 + j) * LDP + nt * 16 + t16] = f2bf(v);
    }
  }
}

// 6 col-tiles accumulated into acc[0..6), weights from global frags
__device__ __forceinline__ void mfma6_g(f32x4* acc, Frags f,
    const u16* __restrict__ wb, int lane)
{
  #pragma unroll
  for (int jt = 0; jt < 6; jt++){
    const u16* wp = wb + jt * 1536 + lane * 8;
    acc[jt] = MFMA(f.a0, *reinterpret_cast<const bf16x8*>(wp),        acc[jt]);
    acc[jt] = MFMA(f.a1, *reinterpret_cast<const bf16x8*>(wp + 512),  acc[jt]);
    acc[jt] = MFMA(f.a2, *reinterpret_cast<const bf16x8*>(wp + 1024), acc[jt]);
  }
}

// ============================================================================
// K_prep2: f32 weights -> bf16 B-fragment layout (direct chunks).
// frag elem (f, l, j): nt=f/3, kc=f%3, n=nt*16+(l&15), k=(l>>4)*8+kc*32+j
__global__ __launch_bounds__(256) void k_prep2(const float* __restrict__ crW,
    const float* __restrict__ drW, const float* __restrict__ gmW2,
    const float* __restrict__ rW12, const float* __restrict__ Whh,
    u16* __restrict__ pWB)
{
  int b = blockIdx.x, tid = threadIdx.x;
  if (b < 7){
    const float* src; int ch;                   // row-major [k][n]
    if      (b == 0){ src = crW;          ch = 0;  }
    else if (b == 1){ src = crW  + 9216;  ch = 1;  }
    else if (b == 2){ src = drW;          ch = 3;  }
    else if (b == 3){ src = drW  + 9216;  ch = 4;  }
    else if (b == 4){ src = gmW2;         ch = 8;  }
    else if (b == 5){ src = rW12;         ch = 10; }
    else            { src = rW12 + 9216;  ch = 11; }
    u16* dst = pWB + ch * FCH;
    #pragma unroll
    for (int i = 0; i < 36; i++){
      int idx = tid + i * 256;
      int f = idx >> 9, rem = idx & 511, l = rem >> 3, j = rem & 7;
      int nt = f / 3, kc = f - nt * 3;
      int n = nt * 16 + (l & 15);
      int k = ((l >> 4) << 3) + kc * 32 + j;
      dst[idx] = f2bf(src[k * 96 + n]);
    }
  } else {
    int bb = b - 7;                             // 0..3 Whh gate chunks
    u16* dst = pWB + (16 + bb) * FCH;
    const float* src = Whh + bb * 9216;         // [n][k]
    #pragma unroll
    for (int i = 0; i < 36; i++){
      int idx = tid + i * 256;
      int f = idx >> 9, rem = idx & 511, l = rem >> 3, j = rem & 7;
      int nt = f / 3, kc = f - nt * 3;
      int n = nt * 16 + (l & 15);
      int k = ((l >> 4) << 3) + kc * 32 + j;
      dst[idx] = f2bf(src[n * 96 + k]);
    }
  }
}

// K_prepadj: static Sudoku adjacency as 96x96 bf16 row-major (0/1 exact).
// Rows/cols >= 81 are zero (kills pad garbage in the MFMA msg kernel).
__global__ __launch_bounds__(256) void k_prepadj(u16* __restrict__ adjM)
{
  int tid = threadIdx.x;
  for (int i = tid; i < 9216; i += 256){
    int m = i / 96, n = i - (i / 96) * 96;
    float v = 0.f;
    if (m < 81 && n < 81 && m != n){
      int rm = m / 9, cm = m - rm * 9;
      int rn = n / 9, cn = n - rn * 9;
      if (rm == rn || cm == cn || ((rm / 3 == rn / 3) && (cm / 3 == cn / 3)))
        v = 1.f;
    }
    adjM[i] = f2bf(v);
  }
}

// K_prepc: folded cell/digit output weights.
// g=0: chunk2 = crW[2] @ W1b, bY = crb[2] @ W1b  (W1b = gmW1 rows 96..191)
// g=1: chunk5 = drW[2] @ W1c, bZ = drb[2] @ W1c  (W1c = gmW1 rows 192..287)
__global__ __launch_bounds__(256) void k_prepc(const float* __restrict__ crW,
    const float* __restrict__ crB, const float* __restrict__ drW,
    const float* __restrict__ drB, const float* __restrict__ gmW1,
    u16* __restrict__ pWB, float* __restrict__ bY, float* __restrict__ bZ)
{
  __shared__ float sM[96 * PST];                // left [k][j]
  __shared__ float sW[96 * PST];                // right [j][n]
  int b = blockIdx.x, g = b / 9, seg = b - g * 9, tid = threadIdx.x;
  const float* L = (g == 0 ? crW : drW) + 2 * 9216;
  const float* R = gmW1 + (g == 0 ? 9216 : 18432);
  for (int i = tid; i < 9216; i += 256){
    int r = i / 96, cc = i - r * 96;
    sM[r * PST + cc] = L[i];
    sW[r * PST + cc] = R[i];
  }
  __syncthreads();
  if (seg == 0){
    const float* bv = (g == 0 ? crB : drB) + 192;
    float* bo = (g == 0 ? bY : bZ);
    for (int n = tid; n < 96; n += 256){
      float a = 0.f;
      for (int j = 0; j < 96; j++) a += bv[j] * sW[j * PST + n];
      bo[n] = a;
    }
  }
  u16* dst = pWB + (g == 0 ? 2 : 5) * FCH;
  #pragma unroll
  for (int i = 0; i < 4; i++){
    int idx = seg * 1024 + tid + i * 256;
    int f = idx >> 9, rem = idx & 511, l = rem >> 3, j = rem & 7;
    int nt = f / 3, kc = f - nt * 3;
    int n = nt * 16 + (l & 15);
    int k = ((l >> 4) << 3) + kc * 32 + j;
    float a = 0.f;
    #pragma unroll 4
    for (int jj = 0; jj < 96; jj++) a += sM[k * PST + jj] * sW[jj * PST + n];
    dst[idx] = f2bf(a);
  }
}

// K_prepf: fused x-path weight Wf = W2b @ Wih^T -> frag chunks 12-15.
__global__ __launch_bounds__(256) void k_prepf(const float* __restrict__ gmW2,
    const float* __restrict__ Wih, u16* __restrict__ pWB)
{
  __shared__ float sW[96 * PST];                // W2b staged, padded stride
  int b = blockIdx.x, g = b / 9, seg = b - g * 9, tid = threadIdx.x;
  for (int i = tid; i < 9216; i += 256){
    int r = i / 96, cc = i - r * 96;
    sW[r * PST + cc] = gmW2[9216 + i];
  }
  __syncthreads();
  u16* dst = pWB + (12 + g) * FCH;
  #pragma unroll
  for (int i = 0; i < 4; i++){
    int idx = seg * 1024 + tid + i * 256;
    int f = idx >> 9, rem = idx & 511, l = rem >> 3, j = rem & 7;
    int nt = f / 3, kc = f - nt * 3;
    int n = nt * 16 + (l & 15);
    int k = ((l >> 4) << 3) + kc * 32 + j;
    const float* wr = Wih + (g * 96 + n) * 96;
    float a = 0.f;
    #pragma unroll 4
    for (int jj = 0; jj < 96; jj++) a += sW[k * PST + jj] * wr[jj];
    dst[idx] = f2bf(a);
  }
}

// K0: tables (f32) + fused LSTM bias bsx = bih + bhh + b2b @ Wih^T
__global__ void k_tables(const float* __restrict__ eW1, const float* __restrict__ eb1,
                         const float* __restrict__ eW2, const float* __restrict__ eb2,
                         const float* __restrict__ gmW1, const float* __restrict__ gmb1,
                         const float* __restrict__ bih, const float* __restrict__ bhh,
                         const float* __restrict__ gmb2, const float* __restrict__ Wih,
                         float* __restrict__ XTab, float* __restrict__ XgTab,
                         float* __restrict__ bsx)
{
  __shared__ float sX[3][96];
  int j = threadIdx.x;
  for (int n = j; n < 384; n += 128){
    float acc = bih[n] + bhh[n];
    const float* wr = Wih + n * 96;
    for (int jj = 0; jj < 96; jj++) acc += gmb2[96 + jj] * wr[jj];
    bsx[n] = acc;
  }
  if (j < 96){
    for (int ch = 0; ch < 3; ch++){
      float acc = eb2[j];
      for (int e = 0; e < 16; e++){
        float hv = fmaxf(eW1[ch * 16 + e] + eb1[e], 0.f);
        acc += hv * eW2[e * 96 + j];
      }
      sX[ch][j] = acc;
      XTab[ch * 96 + j] = acc;
    }
  }
  __syncthreads();
  if (j < 96){
    for (int ch = 0; ch < 3; ch++){
      float acc = gmb1[j];
      for (int k = 0; k < 96; k++) acc += sX[ch][k] * gmW1[k * 96 + j];
      XgTab[ch * 96 + j] = acc;
    }
  }
}

// K_init: h only (c0 read directly on iter 0)
__global__ __launch_bounds__(256) void k_init(const int* __restrict__ inputs,
    const float* __restrict__ XTab, u16* __restrict__ h)
{
  int idx = blockIdx.x * 256 + threadIdx.x;     // exactly MROWS*12
  int m = idx / 12, h8 = idx - m * 12;
  int bn = m / 9, d = m - bn * 9;
  int inp = inputs[bn];
  int ch = (inp == 0) ? 0 : ((inp == d + 1) ? 1 : 2);
  const float* xt = XTab + ch * 96 + h8 * 8;
  u16* hp = h + (size_t)m * 96 + h8 * 8;
  #pragma unroll
  for (int e = 0; e < 8; e++) hp[e] = f2bf(xt[e]);
}

// K_AB3: h -> cr1,cr2,crF = Y;  h -> dr1,dr2,drF = Z. 6 layers, barrier-free.
// Used once before the loop; later iterations produce Y/Z inside k_fuse32.
__global__ __launch_bounds__(256) void k_ab3(const u16* __restrict__ h,
    u16* __restrict__ Y, u16* __restrict__ Z,
    const u16* __restrict__ pWB, const float* __restrict__ crB,
    const float* __restrict__ drB, const float* __restrict__ bY,
    const float* __restrict__ bZ)
{
  __shared__ u16 sA[64 * LDP];                  // wave-private 16-row slices
  const int tid = threadIdx.x, lane = tid & 63, wave = tid >> 6;
  const int wrow = wave * 16;
  const size_t rbase = (size_t)blockIdx.x * 64;

  Frags hf = load_afrags_g(h, rbase + wrow, lane);

  layer_g(hf, pWB, crB, sA, LDP, wrow, true, lane);                  lds_fence();
  Frags f = load_afrags_s(sA, wrow, lane);
  layer_g(f, pWB + 1 * FCH, crB + 96, sA, LDP, wrow, true, lane);    lds_fence();
  f = load_afrags_s(sA, wrow, lane);
  layer_g(f, pWB + 2 * FCH, bY, Y, 96, rbase + wrow, false, lane);
  lds_fence();

  layer_g(hf, pWB + 3 * FCH, drB, sA, LDP, wrow, true, lane);        lds_fence();
  f = load_afrags_s(sA, wrow, lane);
  layer_g(f, pWB + 4 * FCH, drB + 96, sA, LDP, wrow, true, lane);    lds_fence();
  f = load_afrags_s(sA, wrow, lane);
  layer_g(f, pWB + 5 * FCH, bZ, Z, 96, rbase + wrow, false, lane);
}

// K_MSG: digit message via MFMA (blocks 0..1151: Z[b,:,d,:] = adj @ Z[b,:,d,:],
// in-place, staged to LDS in B-frag layout with PADDED frag stride FST) +
// scell (blocks 1152..1637, Y -> Ssum). adjM = static 96x96 bf16 adjacency.
__global__ __launch_bounds__(256) void k_msg(u16* __restrict__ Z,
    const u16* __restrict__ Y, u16* __restrict__ Ssum,
    const u16* __restrict__ adjM)
{
  __shared__ u16 sF[18 * FST];                  // Z-slice B-frags (18.7 KB)
  const int tid = threadIdx.x;
  if (blockIdx.x >= 1152){
    // ---- scell part: Ssum[bn,:] = sum_d Y[bn,d,:] ----
    int idx = (blockIdx.x - 1152) * 256 + tid;  // exactly BN*12
    int bn = idx / 12, h8 = idx - bn * 12;
    const u16* base = Y + (size_t)bn * 864 + h8 * 8;
    float s[8];
    #pragma unroll
    for (int e = 0; e < 8; e++) s[e] = 0.f;
    #pragma unroll
    for (int d = 0; d < 9; d++){
      u16x8 v = *reinterpret_cast<const u16x8*>(base + d * 96);
      #pragma unroll
      for (int e = 0; e < 8; e++) s[e] += bf2f(v[e]);
    }
    u16x8 o;
    #pragma unroll
    for (int e = 0; e < 8; e++) o[e] = f2bf(s[e]);
    *reinterpret_cast<u16x8*>(Ssum + (size_t)bn * 96 + h8 * 8) = o;
    return;
  }
  // ---- msgdigit: OUT[m][c] = sum_n adj[m][n] * Z[n][c], MFMA 16x16x32 ----
  const int b = blockIdx.x / 9, d = blockIdx.x - b * 9;
  const size_t base = ((size_t)b * 729 + d) * 96;
  // stage Z-slice (rows 0..80, zeros 81..95) into padded B-frag layout:
  // elem Z[n][c] -> frag f=(c>>4)*3+(n>>5) at offset l*8+j,
  // l=((n>>3)&3)*16+(c&15), j=n&7
  for (int i = tid; i < 1152; i += 256){        // 96 nodes x 12 k8
    int n = i / 12, k8 = i - (i / 12) * 12;
    u16x8 v;
    if (n < 81){
      v = *reinterpret_cast<const u16x8*>(Z + base + (size_t)n * 864 + k8 * 8);
    } else {
      for (int e = 0; e < 8; e++) v[e] = 0;
    }
    int f = (k8 >> 1) * 3 + (n >> 5);
    int lbase = ((n >> 3) & 3) * 16 + (k8 & 1) * 8;
    u16* p = sF + f * FST + lbase * 8 + (n & 7);
    #pragma unroll
    for (int e = 0; e < 8; e++) p[e * 8] = v[e];
  }
  __syncthreads();
  const int lane = tid & 63, w = tid >> 6;
  const int t16 = lane & 15, q = lane >> 4;
  #pragma unroll
  for (int ti = 0; ti < 9; ti++){               // 36 output tiles / 4 waves
    int t = w + ti * 4;
    int mt = t / 6, nt = t - mt * 6;
    Frags fa = load_afrags_g(adjM, mt * 16, lane);   // static A (L1-hot)
    f32x4 acc = {0.f, 0.f, 0.f, 0.f};
    const u16* bp = sF + nt * 3 * FST + lane * 8;
    acc = MFMA(fa.a0, *reinterpret_cast<const bf16x8*>(bp),           acc);
    acc = MFMA(fa.a1, *reinterpret_cast<const bf16x8*>(bp + FST),     acc);
    acc = MFMA(fa.a2, *reinterpret_cast<const bf16x8*>(bp + 2 * FST), acc);
    int c = nt * 16 + t16;
    #pragma unroll
    for (int jr = 0; jr < 4; jr++){
      int m = mt * 16 + q * 4 + jr;
      if (m < 81) Z[base + (size_t)m * 864 + c] = f2bf(acc[jr]);
    }
  }
}

// ============================================================================
// per-tile LSTM (gates + epilogue). Uniform control flow; called twice.
// cp0..cp5 are the prefetched c-state values for this tile's 6 epilogue elems.
__device__ __forceinline__ void lstm_tile(const u16* sBt, Frags fht,
    float cp0, float cp1, float cp2, float cp3, float cp4, float cp5,
    u16* sAt, float* sGhF, size_t r0, u16* h, float* cout,
    const float* __restrict__ bsx, const u16* __restrict__ pWB,
    int tid, int lane, int w, int t16, int q)
{
  f32x4 acc[6];
  #pragma unroll
  for (int nt = 0; nt < 6; nt++){
    float b = bsx[w * 96 + nt * 16 + t16];
    f32x4 a = {b, b, b, b};
    acc[nt] = a;
  }
  {
    Frags fa = load_afrags_s(sBt, 0, lane);
    mfma6_g(acc, fa, pWB + (12 + w) * FCH, lane);   // x-path: A1 @ Wf_w^T
    mfma6_g(acc, fht, pWB + (16 + w) * FCH, lane);  // h-path: h  @ Whh_w^T
  }
  float cparr[6] = {cp0, cp1, cp2, cp3, cp4, cp5};  // constant-indexed -> regs

  // gate half rows 0..7 (lanes q<2) -> epilogue
  if (q < 2){
    #pragma unroll
    for (int nt = 0; nt < 6; nt++)
      #pragma unroll
      for (int j = 0; j < 4; j++)
        sGhF[(w * 8 + q * 4 + j) * SGX + nt * 16 + t16] = acc[nt][j];
  }
  __syncthreads();
  #pragma unroll
  for (int e = 0; e < 3; e++){
    int idx = e * 256 + tid;                    // rows 0..7
    int r = idx / 96, col = idx - r * 96;
    float iv = sGhF[(0 * 8 + r) * SGX + col];
    float fv = sGhF[(1 * 8 + r) * SGX + col];
    float gv = sGhF[(2 * 8 + r) * SGX + col];
    float ov = sGhF[(3 * 8 + r) * SGX + col];
    size_t m = r0 + r;
    float cn = sigf(fv) * cparr[e] + sigf(iv) * tanhf_(gv);
    float hn = sigf(ov) * tanhf_(cn);
    cout[m * 96 + col] = cn;
    u16 hb = f2bf(hn);
    h[m * 96 + col] = hb;
    sAt[r * LDP + col] = hb;
  }
  __syncthreads();

  // gate half rows 8..15 (lanes q>=2) -> epilogue
  if (q >= 2){
    #pragma unroll
    for (int nt = 0; nt < 6; nt++)
      #pragma unroll
      for (int j = 0; j < 4; j++)
        sGhF[(w * 8 + (q - 2) * 4 + j) * SGX + nt * 16 + t16] = acc[nt][j];
  }
  __syncthreads();
  #pragma unroll
  for (int e = 0; e < 3; e++){
    int idx = (e + 3) * 256 + tid;              // rows 8..15
    int r = idx / 96, col = idx - r * 96;
    float iv = sGhF[(0 * 8 + r - 8) * SGX + col];
    float fv = sGhF[(1 * 8 + r - 8) * SGX + col];
    float gv = sGhF[(2 * 8 + r - 8) * SGX + col];
    float ov = sGhF[(3 * 8 + r - 8) * SGX + col];
    size_t m = r0 + r;
    float cn = sigf(fv) * cparr[e + 3] + sigf(iv) * tanhf_(gv);
    float hn = sigf(ov) * tanhf_(cn);
    cout[m * 96 + col] = cn;
    u16 hb = f2bf(hn);
    h[m * 96 + col] = hb;
    sAt[r * LDP + col] = hb;
  }
  __syncthreads();
}

// K_FUSE32: 32 rows/block as TWO 16-row tiles, phase-interleaved so each
// phase's weights are L1-hot on the second tile (halves L2 weight traffic,
// the dominant per-block cost: 13 chunks x 18 KB vs ~25 KB activations).
// launch_bounds(256,4): proven no-spill config.
__global__ __launch_bounds__(256, 4) void k_fuse32(u16* Y, u16* Z,
    const u16* __restrict__ Ssum,
    const int* __restrict__ inputs, const float* __restrict__ XgTab,
    const u16* __restrict__ pWB, const float* __restrict__ gmb2,
    u16* h, const float* cin, float* cout,
    const float* __restrict__ bsx, const float* __restrict__ rb12,
    const float* __restrict__ rW3, const float* __restrict__ rb3,
    float* __restrict__ out, const float* __restrict__ crB,
    const float* __restrict__ drB, const float* __restrict__ bY,
    const float* __restrict__ bZ, int doAB)
{
  __shared__ u16 sA[2 * 16 * LDP];              // h_new per tile (6.7 KB)
  __shared__ u16 sU[6 * TBUF];                  // union scratch (19.97 KB)
  u16*   sB0  = sU;                             // A1 tile0 (P2-P3)
  u16*   sB1  = sU + TBUF;                      // A1 tile1
  float* sGhF = reinterpret_cast<float*>(sU + 2 * TBUF);  // gates [4][8][SGX]
  const int tid = threadIdx.x, lane = tid & 63, w = tid >> 6;
  const int t16 = lane & 15, q = lane >> 4;
  const size_t rbase = (size_t)blockIdx.x * 32;

  // ---- EARLY: issue HBM reads consumed in later phases ----
  float cp[12];
  #pragma unroll
  for (int e = 0; e < 6; e++){
    int idx = e * 256 + tid;
    int r = idx / 96, col = idx - r * 96;
    cp[e]     = cin[(rbase + r) * 96 + col];
    cp[e + 6] = cin[(rbase + 16 + r) * 96 + col];
  }
  Frags fh0 = load_afrags_g(h, rbase, lane);
  Frags fh1 = load_afrags_g(h, rbase + 16, lane);

  // ---- P1: combine g1 = relu(Xg + (Ssum - Y) + Zd) -> sA[t] ----
  #pragma unroll
  for (int t = 0; t < 2; t++){
    if (tid < 192){
      int rl = tid / 12, kc = tid - (tid / 12) * 12;
      int m = (int)rbase + t * 16 + rl;
      int bn = m / 9, d = m - bn * 9;
      int inp = inputs[bn];
      int ch = (inp == 0) ? 0 : ((inp == d + 1) ? 1 : 2);
      const float* xg = XgTab + ch * 96 + kc * 8;
      u16x8 vy = *reinterpret_cast<const u16x8*>(Y    + (size_t)m * 96 + kc * 8);
      u16x8 vz = *reinterpret_cast<const u16x8*>(Z    + (size_t)m * 96 + kc * 8);
      u16x8 vs = *reinterpret_cast<const u16x8*>(Ssum + (size_t)bn * 96 + kc * 8);
      u16x8 o;
      #pragma unroll
      for (int e = 0; e < 8; e++)
        o[e] = f2bf(fmaxf(xg[e] + bf2f(vs[e]) - bf2f(vy[e]) + bf2f(vz[e]), 0.f));
      *reinterpret_cast<u16x8*>(sA + t * 16 * LDP + rl * LDP + kc * 8) = o;
    }
  }
  __syncthreads();

  // ---- P2: gm2a both tiles (chunk-8 weights L1-hot on tile 1) ----
  {
    Frags f = load_afrags_s(sA, 0, lane);
    layer_split(f, pWB + 8 * FCH, gmb2, sB0, true, lane, w);
    Frags g = load_afrags_s(sA + 16 * LDP, 0, lane);
    layer_split(g, pWB + 8 * FCH, gmb2, sB1, true, lane, w);
  }
  __syncthreads();

  // ---- P3+P4: LSTM per tile (Wf/Whh chunks L1-hot on tile 1) ----
  lstm_tile(sB0, fh0, cp[0], cp[1], cp[2], cp[3], cp[4], cp[5],
            sA, sGhF, rbase, h, cout, bsx, pWB, tid, lane, w, t16, q);
  lstm_tile(sB1, fh1, cp[6], cp[7], cp[8], cp[9], cp[10], cp[11],
            sA + 16 * LDP, sGhF, rbase + 16, h, cout, bsx, pWB,
            tid, lane, w, t16, q);
  // sA[0..2) = h_new for both tiles; sU fully dead -> tail buffers

  // ---- TAIL: barrier-free per-wave chains over both tiles ----
  if (w == 0){
    // readout: r1 -> r2 -> dot -> out (t0 then t1; weights hot on t1)
    u16* bA = sU + 0 * TBUF;
    u16* bB = sU + 1 * TBUF;
    #pragma unroll
    for (int t = 0; t < 2; t++){
      const u16* src = sA + t * 16 * LDP;
      Frags f = load_afrags_s(src, 0, lane);
      layer_g(f, pWB + 10 * FCH, rb12, bA, LDP, 0, true, lane);      lds_fence();
      f = load_afrags_s(bA, 0, lane);
      layer_g(f, pWB + 11 * FCH, rb12 + 96, bB, LDP, 0, true, lane); lds_fence();
      int row = lane >> 2, part = lane & 3;
      float s = 0.f;
      const u16* rp = bB + row * LDP + part * 24;
      #pragma unroll
      for (int k = 0; k < 24; k++) s += bf2f(rp[k]) * rW3[part * 24 + k];
      s += __shfl_xor(s, 1);
      s += __shfl_xor(s, 2);
      if (part == 0) out[rbase + t * 16 + row] = s + rb3[0];
      lds_fence();
    }
  } else if (w == 1 && doAB){
    // cell-relation chain: cr1 -> cr2 -> crF -> Y
    u16* bA = sU + 2 * TBUF;
    u16* bB = sU + 3 * TBUF;
    #pragma unroll
    for (int t = 0; t < 2; t++){
      const u16* src = sA + t * 16 * LDP;
      Frags f = load_afrags_s(src, 0, lane);
      layer_g(f, pWB + 0 * FCH, crB, bA, LDP, 0, true, lane);        lds_fence();
      f = load_afrags_s(bA, 0, lane);
      layer_g(f, pWB + 1 * FCH, crB + 96, bB, LDP, 0, true, lane);   lds_fence();
      f = load_afrags_s(bB, 0, lane);
      layer_g(f, pWB + 2 * FCH, bY, Y, 96, rbase + t * 16, false, lane);
      lds_fence();
    }
  } else if (w == 2 && doAB){
    // digit-relation chain: dr1 -> dr2 -> drF -> Z
    u16* bA = sU + 4 * TBUF;
    u16* bB = sU + 5 * TBUF;
    #pragma unroll
    for (int t = 0; t < 2; t++){
      const u16* src = sA + t * 16 * LDP;
      Frags f = load_afrags_s(src, 0, lane);
      layer_g(f, pWB + 3 * FCH, drB, bA, LDP, 0, true, lane);        lds_fence();
      f = load_afrags_s(bA, 0, lane);
      layer_g(f, pWB + 4 * FCH, drB + 96, bB, LDP, 0, true, lane);   lds_fence();
      f = load_afrags_s(bB, 0, lane);
      layer_g(f, pWB + 5 * FCH, bZ, Z, 96, rbase + t * 16, false, lane);
      lds_fence();
    }
  }
}

// ============================================================================
extern "C" void kernel_launch(void* const* d_in, const int* in_sizes, int n_in,
                              void* d_out, int out_size, void* d_ws, size_t ws_size,
                              hipStream_t stream)
{
  (void)in_sizes; (void)n_in; (void)out_size; (void)ws_size;
  const int*   inputs = (const int*)d_in[0];
  const float* c0     = (const float*)d_in[1];
  const float* eW1  = (const float*)d_in[4];
  const float* eb1  = (const float*)d_in[5];
  const float* eW2  = (const float*)d_in[6];
  const float* eb2  = (const float*)d_in[7];
  const float* crW  = (const float*)d_in[8];
  const float* crB  = (const float*)d_in[9];
  const float* drW  = (const float*)d_in[10];
  const float* drB  = (const float*)d_in[11];
  const float* gmW1 = (const float*)d_in[12];
  const float* gmb1 = (const float*)d_in[13];
  const float* gmW2 = (const float*)d_in[14];
  const float* gmb2 = (const float*)d_in[15];
  const float* Wih  = (const float*)d_in[16];
  const float* Whh  = (const float*)d_in[17];
  const float* bih  = (const float*)d_in[18];
  const float* bhh  = (const float*)d_in[19];
  const float* rW12 = (const float*)d_in[20];
  const float* rb12 = (const float*)d_in[21];
  const float* rW3  = (const float*)d_in[22];
  const float* rb3  = (const float*)d_in[23];

  char* ws = (char*)d_ws;
  float* XgTab = (float*)(ws);
  float* XTab  = (float*)(ws + 4096);
  float* bsx   = (float*)(ws + 6144);            // 384*4 = 1536 B
  float* bY    = (float*)(ws + 7680);            // 96*4
  float* bZ    = (float*)(ws + 8064);            // 96*4, ends 8448
  u16*   pWB   = (u16*)(ws + 8704);              // 20*9216*2 = 368640 B
  u16* h  = (u16*)(ws + 409600);
  u16* B1 = h  + (size_t)MROWS * 96;             // Y
  u16* B2 = B1 + (size_t)MROWS * 96;             // Z
  float* c = (float*)(B2 + (size_t)MROWS * 96);
  u16* Ssum = (u16*)(c + (size_t)MROWS * 96);    // BN*96 bf16
  u16* adjM = Ssum + (size_t)BN * 96;            // 96*96 bf16 (18 KB)
  float* out = (float*)d_out;

  k_prep2<<<11, 256, 0, stream>>>(crW, drW, gmW2, rW12, Whh, pWB);
  k_prepc<<<18, 256, 0, stream>>>(crW, crB, drW, drB, gmW1, pWB, bY, bZ);
  k_prepf<<<36, 256, 0, stream>>>(gmW2, Wih, pWB);
  k_prepadj<<<1, 256, 0, stream>>>(adjM);
  k_tables<<<1, 128, 0, stream>>>(eW1, eb1, eW2, eb2, gmW1, gmb1, bih, bhh,
                                  gmb2, Wih, XTab, XgTab, bsx);
  k_init<<<(MROWS * 12) / 256, 256, 0, stream>>>(inputs, XTab, h);
  k_ab3<<<GRID_TILE, 256, 0, stream>>>(h, B1, B2, pWB, crB, drB, bY, bZ);

  for (int it = 0; it < 4; ++it){
    const float* cin = (it == 0) ? c0 : c;
    k_msg<<<1152 + 486, 256, 0, stream>>>(B2, B1, Ssum, adjM);
    k_fuse32<<<FUSE_GRID, 256, 0, stream>>>(B1, B2, Ssum, inputs, XgTab, pWB,
                                            gmb2, h, cin, c, bsx, rb12, rW3, rb3,
                                            out + (size_t)it * MROWS,
                                            crB, drB, bY, bZ, (it < 3) ? 1 : 0);
  }
}

// Round 16
// 628.197 us; speedup vs baseline: 1.4011x; 1.4011x over previous
//
#include <hip/hip_runtime.h>
#include <hip/hip_bf16.h>

typedef unsigned short u16;
typedef __bf16 bf16x8 __attribute__((ext_vector_type(8)));   // MFMA A/B operand (4 VGPRs)
typedef float  f32x4  __attribute__((ext_vector_type(4)));   // MFMA C/D operand
typedef u16    u16x8  __attribute__((ext_vector_type(8)));

#define HID   96
#define LDP   104          // padded LDS row stride for activation slices
#define MROWS 93312        // B*N*D
#define BN    10368        // B*N
#define GRID_TILE 1458     // MROWS/64
#define FUSE_GRID 5832     // MROWS/16
#define SGX   100          // f32 LDS stride gate exchange: 4*100 ≡ 16 mod 32 → 2-way (free)
#define PST   97           // padded f32 stride for prep staging (kills 32-way conflicts)
#define TBUF  1664         // u16 elems per 16-row tail buffer (16*LDP)
#define FST   520          // padded u16 frag stride in k_msg LDS (f-step of 3 → bank+12)

// B-fragment-ordered weights: 20 chunks x 18 frags x 512 elems (1KB frags)
// chunk: 0 cr1, 1 cr2, 2 crF=crW2@W1b, 3 dr1, 4 dr2, 5 drF=drW2@W1c,
//        8 gm2a, 10-11 rW12, 12-15 Wf=W2b@Wih^T (gates i,f,g,o), 16-19 Whh
#define FCH 9216           // elems per chunk (18*512)

#define MFMA(a,b,c) __builtin_amdgcn_mfma_f32_16x16x32_bf16((a),(b),(c),0,0,0)

__device__ __forceinline__ float bf2f(u16 x){
  union { float f; unsigned u; } v; v.u = ((unsigned)x) << 16; return v.f;
}
// native cast -> v_cvt_pk_bf16_f32 (RNE, 1 instr / 2 values when paired)
__device__ __forceinline__ u16 f2bf(float f){
  union { __bf16 b; u16 u; } v; v.b = (__bf16)f; return v.u;
}
__device__ __forceinline__ float frcp(float x){ return __builtin_amdgcn_rcpf(x); }
__device__ __forceinline__ float sigf(float x){ return frcp(1.f + __expf(-x)); }
__device__ __forceinline__ float tanhf_(float x){
  float xx = fminf(fmaxf(x, -15.f), 15.f);
  float e = __expf(-2.f * xx);
  return (1.f - e) * frcp(1.f + e);
}
// in-wave LDS write->read ordering (wave-private slices only)
__device__ __forceinline__ void lds_fence(){
  asm volatile("s_waitcnt lgkmcnt(0)" ::: "memory");
}

// ---- fragment loaders -------------------------------------------------------
struct Frags { bf16x8 a0, a1, a2; };

__device__ __forceinline__ Frags load_afrags_g(const u16* __restrict__ A, size_t row0, int lane){
  int t16 = lane & 15, q = lane >> 4;
  const u16* p = A + (row0 + (size_t)t16) * 96 + q * 8;
  Frags f;
  f.a0 = *reinterpret_cast<const bf16x8*>(p);
  f.a1 = *reinterpret_cast<const bf16x8*>(p + 32);
  f.a2 = *reinterpret_cast<const bf16x8*>(p + 64);
  return f;
}
__device__ __forceinline__ Frags load_afrags_s(const u16* sA, int row0, int lane){
  int t16 = lane & 15, q = lane >> 4;
  const u16* p = sA + (row0 + t16) * LDP + q * 8;
  Frags f;
  f.a0 = *reinterpret_cast<const bf16x8*>(p);
  f.a1 = *reinterpret_cast<const bf16x8*>(p + 32);
  f.a2 = *reinterpret_cast<const bf16x8*>(p + 64);
  return f;
}

// ---- one 16x96 layer, weights as global B-frags (L1/L2-resident) ------------
__device__ __forceinline__ void layer_g(Frags f, const u16* __restrict__ wb,
    const float* __restrict__ bias, u16* dst, int dstStride, size_t rowBase,
    bool relu, int lane)
{
  int t16 = lane & 15, q = lane >> 4;
  #pragma unroll
  for (int nt = 0; nt < 6; nt++){
    float b = bias ? bias[nt * 16 + t16] : 0.f;
    f32x4 acc = {b, b, b, b};
    const u16* wp = wb + nt * 1536 + lane * 8;
    acc = MFMA(f.a0, *reinterpret_cast<const bf16x8*>(wp),        acc);
    acc = MFMA(f.a1, *reinterpret_cast<const bf16x8*>(wp + 512),  acc);
    acc = MFMA(f.a2, *reinterpret_cast<const bf16x8*>(wp + 1024), acc);
    #pragma unroll
    for (int j = 0; j < 4; j++){
      float v = acc[j];
      if (relu) v = fmaxf(v, 0.f);
      dst[(rowBase + q * 4 + j) * (size_t)dstStride + nt * 16 + t16] = f2bf(v);
    }
  }
}

// 16-row layer split across 4 waves by col-tile (wave w: nt = w, w+4).
// Cross-wave data: caller must __syncthreads() before reading dst frags.
__device__ __forceinline__ void layer_split(Frags f, const u16* __restrict__ wb,
    const float* __restrict__ bias, u16* dst, bool relu, int lane, int w)
{
  int t16 = lane & 15, q = lane >> 4;
  #pragma unroll
  for (int nt = w; nt < 6; nt += 4){
    float b = bias ? bias[nt * 16 + t16] : 0.f;
    f32x4 acc = {b, b, b, b};
    const u16* wp = wb + nt * 1536 + lane * 8;
    acc = MFMA(f.a0, *reinterpret_cast<const bf16x8*>(wp),        acc);
    acc = MFMA(f.a1, *reinterpret_cast<const bf16x8*>(wp + 512),  acc);
    acc = MFMA(f.a2, *reinterpret_cast<const bf16x8*>(wp + 1024), acc);
    #pragma unroll
    for (int j = 0; j < 4; j++){
      float v = acc[j];
      if (relu) v = fmaxf(v, 0.f);
      dst[(q * 4 + j) * LDP + nt * 16 + t16] = f2bf(v);
    }
  }
}

// 6 col-tiles accumulated into acc[0..6), weights from global frags
__device__ __forceinline__ void mfma6_g(f32x4* acc, Frags f,
    const u16* __restrict__ wb, int lane)
{
  #pragma unroll
  for (int jt = 0; jt < 6; jt++){
    const u16* wp = wb + jt * 1536 + lane * 8;
    acc[jt] = MFMA(f.a0, *reinterpret_cast<const bf16x8*>(wp),        acc[jt]);
    acc[jt] = MFMA(f.a1, *reinterpret_cast<const bf16x8*>(wp + 512),  acc[jt]);
    acc[jt] = MFMA(f.a2, *reinterpret_cast<const bf16x8*>(wp + 1024), acc[jt]);
  }
}

// ============================================================================
// K_prep2: f32 weights -> bf16 B-fragment layout (direct chunks).
// frag elem (f, l, j): nt=f/3, kc=f%3, n=nt*16+(l&15), k=(l>>4)*8+kc*32+j
__global__ __launch_bounds__(256) void k_prep2(const float* __restrict__ crW,
    const float* __restrict__ drW, const float* __restrict__ gmW2,
    const float* __restrict__ rW12, const float* __restrict__ Whh,
    u16* __restrict__ pWB)
{
  int b = blockIdx.x, tid = threadIdx.x;
  if (b < 7){
    const float* src; int ch;                   // row-major [k][n]
    if      (b == 0){ src = crW;          ch = 0;  }
    else if (b == 1){ src = crW  + 9216;  ch = 1;  }
    else if (b == 2){ src = drW;          ch = 3;  }
    else if (b == 3){ src = drW  + 9216;  ch = 4;  }
    else if (b == 4){ src = gmW2;         ch = 8;  }
    else if (b == 5){ src = rW12;         ch = 10; }
    else            { src = rW12 + 9216;  ch = 11; }
    u16* dst = pWB + ch * FCH;
    #pragma unroll
    for (int i = 0; i < 36; i++){
      int idx = tid + i * 256;
      int f = idx >> 9, rem = idx & 511, l = rem >> 3, j = rem & 7;
      int nt = f / 3, kc = f - nt * 3;
      int n = nt * 16 + (l & 15);
      int k = ((l >> 4) << 3) + kc * 32 + j;
      dst[idx] = f2bf(src[k * 96 + n]);
    }
  } else {
    int bb = b - 7;                             // 0..3 Whh gate chunks
    u16* dst = pWB + (16 + bb) * FCH;
    const float* src = Whh + bb * 9216;         // [n][k]
    #pragma unroll
    for (int i = 0; i < 36; i++){
      int idx = tid + i * 256;
      int f = idx >> 9, rem = idx & 511, l = rem >> 3, j = rem & 7;
      int nt = f / 3, kc = f - nt * 3;
      int n = nt * 16 + (l & 15);
      int k = ((l >> 4) << 3) + kc * 32 + j;
      dst[idx] = f2bf(src[n * 96 + k]);
    }
  }
}

// K_prepadj: static Sudoku adjacency as 96x96 bf16 row-major (0/1 exact).
// Rows/cols >= 81 are zero (kills pad garbage in the MFMA msg kernel).
__global__ __launch_bounds__(256) void k_prepadj(u16* __restrict__ adjM)
{
  int tid = threadIdx.x;
  for (int i = tid; i < 9216; i += 256){
    int m = i / 96, n = i - (i / 96) * 96;
    float v = 0.f;
    if (m < 81 && n < 81 && m != n){
      int rm = m / 9, cm = m - rm * 9;
      int rn = n / 9, cn = n - rn * 9;
      if (rm == rn || cm == cn || ((rm / 3 == rn / 3) && (cm / 3 == cn / 3)))
        v = 1.f;
    }
    adjM[i] = f2bf(v);
  }
}

// K_prepc: folded cell/digit output weights.
// g=0: chunk2 = crW[2] @ W1b, bY = crb[2] @ W1b  (W1b = gmW1 rows 96..191)
// g=1: chunk5 = drW[2] @ W1c, bZ = drb[2] @ W1c  (W1c = gmW1 rows 192..287)
__global__ __launch_bounds__(256) void k_prepc(const float* __restrict__ crW,
    const float* __restrict__ crB, const float* __restrict__ drW,
    const float* __restrict__ drB, const float* __restrict__ gmW1,
    u16* __restrict__ pWB, float* __restrict__ bY, float* __restrict__ bZ)
{
  __shared__ float sM[96 * PST];                // left [k][j]
  __shared__ float sW[96 * PST];                // right [j][n]
  int b = blockIdx.x, g = b / 9, seg = b - g * 9, tid = threadIdx.x;
  const float* L = (g == 0 ? crW : drW) + 2 * 9216;
  const float* R = gmW1 + (g == 0 ? 9216 : 18432);
  for (int i = tid; i < 9216; i += 256){
    int r = i / 96, cc = i - r * 96;
    sM[r * PST + cc] = L[i];
    sW[r * PST + cc] = R[i];
  }
  __syncthreads();
  if (seg == 0){
    const float* bv = (g == 0 ? crB : drB) + 192;
    float* bo = (g == 0 ? bY : bZ);
    for (int n = tid; n < 96; n += 256){
      float a = 0.f;
      for (int j = 0; j < 96; j++) a += bv[j] * sW[j * PST + n];
      bo[n] = a;
    }
  }
  u16* dst = pWB + (g == 0 ? 2 : 5) * FCH;
  #pragma unroll
  for (int i = 0; i < 4; i++){
    int idx = seg * 1024 + tid + i * 256;
    int f = idx >> 9, rem = idx & 511, l = rem >> 3, j = rem & 7;
    int nt = f / 3, kc = f - nt * 3;
    int n = nt * 16 + (l & 15);
    int k = ((l >> 4) << 3) + kc * 32 + j;
    float a = 0.f;
    #pragma unroll 4
    for (int jj = 0; jj < 96; jj++) a += sM[k * PST + jj] * sW[jj * PST + n];
    dst[idx] = f2bf(a);
  }
}

// K_prepf: fused x-path weight Wf = W2b @ Wih^T -> frag chunks 12-15.
__global__ __launch_bounds__(256) void k_prepf(const float* __restrict__ gmW2,
    const float* __restrict__ Wih, u16* __restrict__ pWB)
{
  __shared__ float sW[96 * PST];                // W2b staged, padded stride
  int b = blockIdx.x, g = b / 9, seg = b - g * 9, tid = threadIdx.x;
  for (int i = tid; i < 9216; i += 256){
    int r = i / 96, cc = i - r * 96;
    sW[r * PST + cc] = gmW2[9216 + i];
  }
  __syncthreads();
  u16* dst = pWB + (12 + g) * FCH;
  #pragma unroll
  for (int i = 0; i < 4; i++){
    int idx = seg * 1024 + tid + i * 256;
    int f = idx >> 9, rem = idx & 511, l = rem >> 3, j = rem & 7;
    int nt = f / 3, kc = f - nt * 3;
    int n = nt * 16 + (l & 15);
    int k = ((l >> 4) << 3) + kc * 32 + j;
    const float* wr = Wih + (g * 96 + n) * 96;
    float a = 0.f;
    #pragma unroll 4
    for (int jj = 0; jj < 96; jj++) a += sW[k * PST + jj] * wr[jj];
    dst[idx] = f2bf(a);
  }
}

// K0: tables (f32) + fused LSTM bias bsx = bih + bhh + b2b @ Wih^T
__global__ void k_tables(const float* __restrict__ eW1, const float* __restrict__ eb1,
                         const float* __restrict__ eW2, const float* __restrict__ eb2,
                         const float* __restrict__ gmW1, const float* __restrict__ gmb1,
                         const float* __restrict__ bih, const float* __restrict__ bhh,
                         const float* __restrict__ gmb2, const float* __restrict__ Wih,
                         float* __restrict__ XTab, float* __restrict__ XgTab,
                         float* __restrict__ bsx)
{
  __shared__ float sX[3][96];
  int j = threadIdx.x;
  for (int n = j; n < 384; n += 128){
    float acc = bih[n] + bhh[n];
    const float* wr = Wih + n * 96;
    for (int jj = 0; jj < 96; jj++) acc += gmb2[96 + jj] * wr[jj];
    bsx[n] = acc;
  }
  if (j < 96){
    for (int ch = 0; ch < 3; ch++){
      float acc = eb2[j];
      for (int e = 0; e < 16; e++){
        float hv = fmaxf(eW1[ch * 16 + e] + eb1[e], 0.f);
        acc += hv * eW2[e * 96 + j];
      }
      sX[ch][j] = acc;
      XTab[ch * 96 + j] = acc;
    }
  }
  __syncthreads();
  if (j < 96){
    for (int ch = 0; ch < 3; ch++){
      float acc = gmb1[j];
      for (int k = 0; k < 96; k++) acc += sX[ch][k] * gmW1[k * 96 + j];
      XgTab[ch * 96 + j] = acc;
    }
  }
}

// K_init: h only (c0 read directly on iter 0)
__global__ __launch_bounds__(256) void k_init(const int* __restrict__ inputs,
    const float* __restrict__ XTab, u16* __restrict__ h)
{
  int idx = blockIdx.x * 256 + threadIdx.x;     // exactly MROWS*12
  int m = idx / 12, h8 = idx - m * 12;
  int bn = m / 9, d = m - bn * 9;
  int inp = inputs[bn];
  int ch = (inp == 0) ? 0 : ((inp == d + 1) ? 1 : 2);
  const float* xt = XTab + ch * 96 + h8 * 8;
  u16* hp = h + (size_t)m * 96 + h8 * 8;
  #pragma unroll
  for (int e = 0; e < 8; e++) hp[e] = f2bf(xt[e]);
}

// K_AB3: h -> cr1,cr2,crF = Y;  h -> dr1,dr2,drF = Z. 6 layers, barrier-free.
// Used once before the loop; later iterations produce Y/Z inside k_fuse16x.
__global__ __launch_bounds__(256) void k_ab3(const u16* __restrict__ h,
    u16* __restrict__ Y, u16* __restrict__ Z,
    const u16* __restrict__ pWB, const float* __restrict__ crB,
    const float* __restrict__ drB, const float* __restrict__ bY,
    const float* __restrict__ bZ)
{
  __shared__ u16 sA[64 * LDP];                  // wave-private 16-row slices
  const int tid = threadIdx.x, lane = tid & 63, wave = tid >> 6;
  const int wrow = wave * 16;
  const size_t rbase = (size_t)blockIdx.x * 64;

  Frags hf = load_afrags_g(h, rbase + wrow, lane);

  layer_g(hf, pWB, crB, sA, LDP, wrow, true, lane);                  lds_fence();
  Frags f = load_afrags_s(sA, wrow, lane);
  layer_g(f, pWB + 1 * FCH, crB + 96, sA, LDP, wrow, true, lane);    lds_fence();
  f = load_afrags_s(sA, wrow, lane);
  layer_g(f, pWB + 2 * FCH, bY, Y, 96, rbase + wrow, false, lane);
  lds_fence();

  layer_g(hf, pWB + 3 * FCH, drB, sA, LDP, wrow, true, lane);        lds_fence();
  f = load_afrags_s(sA, wrow, lane);
  layer_g(f, pWB + 4 * FCH, drB + 96, sA, LDP, wrow, true, lane);    lds_fence();
  f = load_afrags_s(sA, wrow, lane);
  layer_g(f, pWB + 5 * FCH, bZ, Z, 96, rbase + wrow, false, lane);
}

// K_MSG: digit message via MFMA (blocks 0..1151: Z[b,:,d,:] = adj @ Z[b,:,d,:],
// in-place, staged to LDS in B-frag layout with PADDED frag stride FST --
// the 12 lanes sharing n land on 6 distinct banks instead of 1) + scell
// (blocks 1152..1637, Y -> Ssum). adjM = static 96x96 bf16 adjacency.
__global__ __launch_bounds__(256) void k_msg(u16* __restrict__ Z,
    const u16* __restrict__ Y, u16* __restrict__ Ssum,
    const u16* __restrict__ adjM)
{
  __shared__ u16 sF[18 * FST];                  // Z-slice B-frags (18.7 KB)
  const int tid = threadIdx.x;
  if (blockIdx.x >= 1152){
    // ---- scell part: Ssum[bn,:] = sum_d Y[bn,d,:] ----
    int idx = (blockIdx.x - 1152) * 256 + tid;  // exactly BN*12
    int bn = idx / 12, h8 = idx - bn * 12;
    const u16* base = Y + (size_t)bn * 864 + h8 * 8;
    float s[8];
    #pragma unroll
    for (int e = 0; e < 8; e++) s[e] = 0.f;
    #pragma unroll
    for (int d = 0; d < 9; d++){
      u16x8 v = *reinterpret_cast<const u16x8*>(base + d * 96);
      #pragma unroll
      for (int e = 0; e < 8; e++) s[e] += bf2f(v[e]);
    }
    u16x8 o;
    #pragma unroll
    for (int e = 0; e < 8; e++) o[e] = f2bf(s[e]);
    *reinterpret_cast<u16x8*>(Ssum + (size_t)bn * 96 + h8 * 8) = o;
    return;
  }
  // ---- msgdigit: OUT[m][c] = sum_n adj[m][n] * Z[n][c], MFMA 16x16x32 ----
  const int b = blockIdx.x / 9, d = blockIdx.x - b * 9;
  const size_t base = ((size_t)b * 729 + d) * 96;
  // stage Z-slice (rows 0..80, zeros 81..95) into padded B-frag layout:
  // elem Z[n][c] -> frag f=(c>>4)*3+(n>>5) at offset l*8+j,
  // l=((n>>3)&3)*16+(c&15), j=n&7
  for (int i = tid; i < 1152; i += 256){        // 96 nodes x 12 k8
    int n = i / 12, k8 = i - (i / 12) * 12;
    u16x8 v;
    if (n < 81){
      v = *reinterpret_cast<const u16x8*>(Z + base + (size_t)n * 864 + k8 * 8);
    } else {
      for (int e = 0; e < 8; e++) v[e] = 0;
    }
    int f = (k8 >> 1) * 3 + (n >> 5);
    int lbase = ((n >> 3) & 3) * 16 + (k8 & 1) * 8;
    u16* p = sF + f * FST + lbase * 8 + (n & 7);
    #pragma unroll
    for (int e = 0; e < 8; e++) p[e * 8] = v[e];
  }
  __syncthreads();
  const int lane = tid & 63, w = tid >> 6;
  const int t16 = lane & 15, q = lane >> 4;
  #pragma unroll
  for (int ti = 0; ti < 9; ti++){               // 36 output tiles / 4 waves
    int t = w + ti * 4;
    int mt = t / 6, nt = t - mt * 6;
    Frags fa = load_afrags_g(adjM, mt * 16, lane);   // static A (L1-hot)
    f32x4 acc = {0.f, 0.f, 0.f, 0.f};
    const u16* bp = sF + nt * 3 * FST + lane * 8;
    acc = MFMA(fa.a0, *reinterpret_cast<const bf16x8*>(bp),           acc);
    acc = MFMA(fa.a1, *reinterpret_cast<const bf16x8*>(bp + FST),     acc);
    acc = MFMA(fa.a2, *reinterpret_cast<const bf16x8*>(bp + 2 * FST), acc);
    int c = nt * 16 + t16;
    #pragma unroll
    for (int jr = 0; jr < 4; jr++){
      int m = mt * 16 + q * 4 + jr;
      if (m < 81) Z[base + (size_t)m * 864 + c] = f2bf(acc[jr]);
    }
  }
}

// ============================================================================
// K_FUSE16X: 16-row blocks; combine -> gm2a -> LSTM -> barrier-free tail.
// launch_bounds(256,4): the PROVEN config (VGPR 64, no spills). All attempts
// to raise per-block work or occupancy ((256,6)/(256,8)/64-row/dual-tile)
// forced the allocator below natural need -> massive scratch spills.
// sU union region (19968 B): sB (A1) / sGh gates / tail buffers.
__global__ __launch_bounds__(256, 4) void k_fuse16x(u16* Y, u16* Z,
    const u16* __restrict__ Ssum,
    const int* __restrict__ inputs, const float* __restrict__ XgTab,
    const u16* __restrict__ pWB, const float* __restrict__ gmb2,
    u16* h, const float* cin, float* cout,
    const float* __restrict__ bsx, const float* __restrict__ rb12,
    const float* __restrict__ rW3, const float* __restrict__ rb3,
    float* __restrict__ out, const float* __restrict__ crB,
    const float* __restrict__ drB, const float* __restrict__ bY,
    const float* __restrict__ bZ, int doAB)
{
  __shared__ u16 sA[16 * LDP];                  // g1 / h_new (3.3 KB)
  __shared__ u16 sU[6 * TBUF];                  // union scratch (19.97 KB)
  u16*   sB   = sU;                             // A1 (P2-P3)
  float* sGhF = reinterpret_cast<float*>(sU + TBUF);  // gates [4][8][SGX] (P4)
  const int tid = threadIdx.x, lane = tid & 63, w = tid >> 6;
  const int t16 = lane & 15, q = lane >> 4;
  const size_t rbase = (size_t)blockIdx.x * 16;

  // ---- EARLY: issue HBM reads consumed in later phases ----
  float cpre[6];
  #pragma unroll
  for (int e = 0; e < 6; e++){
    int idx = e * 256 + tid;
    int r = idx / 96, col = idx - r * 96;
    cpre[e] = cin[(rbase + r) * 96 + col];
  }
  Frags fh = load_afrags_g(h, rbase, lane);     // old h (own rows)

  // ---- P1: combine g1 = relu(Xg + (Ssum - Y) + Zd) -> sA ----
  if (tid < 192){
    int rl = tid / 12, kc = tid - rl * 12;
    int m = (int)rbase + rl;
    int bn = m / 9, d = m - bn * 9;
    int inp = inputs[bn];
    int ch = (inp == 0) ? 0 : ((inp == d + 1) ? 1 : 2);
    const float* xg = XgTab + ch * 96 + kc * 8;
    u16x8 vy = *reinterpret_cast<const u16x8*>(Y    + (size_t)m * 96 + kc * 8);
    u16x8 vz = *reinterpret_cast<const u16x8*>(Z    + (size_t)m * 96 + kc * 8);
    u16x8 vs = *reinterpret_cast<const u16x8*>(Ssum + (size_t)bn * 96 + kc * 8);
    u16x8 o;
    #pragma unroll
    for (int e = 0; e < 8; e++)
      o[e] = f2bf(fmaxf(xg[e] + bf2f(vs[e]) - bf2f(vy[e]) + bf2f(vz[e]), 0.f));
    *reinterpret_cast<u16x8*>(sA + rl * LDP + kc * 8) = o;
  }
  __syncthreads();

  // ---- P2: gm2a (wave-split col-tiles) -> sB (A1) ----
  {
    Frags f = load_afrags_s(sA, 0, lane);
    layer_split(f, pWB + 8 * FCH, gmb2, sB, true, lane, w);
  }
  __syncthreads();

  // ---- P3: LSTM gates, wave w = gate w ----
  f32x4 acc[6];
  #pragma unroll
  for (int nt = 0; nt < 6; nt++){
    float b = bsx[w * 96 + nt * 16 + t16];
    f32x4 a = {b, b, b, b};
    acc[nt] = a;
  }
  {
    Frags fa = load_afrags_s(sB, 0, lane);
    mfma6_g(acc, fa, pWB + (12 + w) * FCH, lane);   // x-path: A1 @ Wf_w^T
    mfma6_g(acc, fh, pWB + (16 + w) * FCH, lane);   // h-path: h  @ Whh_w^T
  }

  // ---- P4a: gate half rows 0..7 (lanes q<2) -> epilogue ----
  if (q < 2){
    #pragma unroll
    for (int nt = 0; nt < 6; nt++)
      #pragma unroll
      for (int j = 0; j < 4; j++)
        sGhF[(w * 8 + q * 4 + j) * SGX + nt * 16 + t16] = acc[nt][j];
  }
  __syncthreads();
  #pragma unroll
  for (int e = 0; e < 3; e++){
    int idx = e * 256 + tid;                    // 0..767 -> rows 0..7
    int r = idx / 96, col = idx - r * 96;
    float iv = sGhF[(0 * 8 + r) * SGX + col];
    float fv = sGhF[(1 * 8 + r) * SGX + col];
    float gv = sGhF[(2 * 8 + r) * SGX + col];
    float ov = sGhF[(3 * 8 + r) * SGX + col];
    size_t m = rbase + r;
    float cn = sigf(fv) * cpre[e] + sigf(iv) * tanhf_(gv);
    float hn = sigf(ov) * tanhf_(cn);
    cout[m * 96 + col] = cn;
    u16 hb = f2bf(hn);
    h[m * 96 + col] = hb;
    sA[r * LDP + col] = hb;
  }
  __syncthreads();

  // ---- P4b: gate half rows 8..15 (lanes q>=2) -> epilogue ----
  if (q >= 2){
    #pragma unroll
    for (int nt = 0; nt < 6; nt++)
      #pragma unroll
      for (int j = 0; j < 4; j++)
        sGhF[(w * 8 + (q - 2) * 4 + j) * SGX + nt * 16 + t16] = acc[nt][j];
  }
  __syncthreads();
  #pragma unroll
  for (int e = 0; e < 3; e++){
    int idx = (e + 3) * 256 + tid;              // 768..1535 -> rows 8..15
    int r = idx / 96, col = idx - r * 96;
    float iv = sGhF[(0 * 8 + r - 8) * SGX + col];
    float fv = sGhF[(1 * 8 + r - 8) * SGX + col];
    float gv = sGhF[(2 * 8 + r - 8) * SGX + col];
    float ov = sGhF[(3 * 8 + r - 8) * SGX + col];
    size_t m = rbase + r;
    float cn = sigf(fv) * cpre[e + 3] + sigf(iv) * tanhf_(gv);
    float hn = sigf(ov) * tanhf_(cn);
    cout[m * 96 + col] = cn;
    u16 hb = f2bf(hn);
    h[m * 96 + col] = hb;
    sA[r * LDP + col] = hb;
  }
  __syncthreads();                               // sA = h_new, visible to all

  // ---- TAIL: barrier-free per-wave chains (sU fully dead -> 6 tail bufs) ----
  if (w == 0){
    // readout: r1 -> r2 -> dot -> out
    u16* bA = sU + 0 * TBUF;
    u16* bB = sU + 1 * TBUF;
    Frags f = load_afrags_s(sA, 0, lane);
    layer_g(f, pWB + 10 * FCH, rb12, bA, LDP, 0, true, lane);        lds_fence();
    f = load_afrags_s(bA, 0, lane);
    layer_g(f, pWB + 11 * FCH, rb12 + 96, bB, LDP, 0, true, lane);   lds_fence();
    int row = lane >> 2, part = lane & 3;
    float s = 0.f;
    const u16* rp = bB + row * LDP + part * 24;
    #pragma unroll
    for (int k = 0; k < 24; k++) s += bf2f(rp[k]) * rW3[part * 24 + k];
    s += __shfl_xor(s, 1);
    s += __shfl_xor(s, 2);
    if (part == 0) out[rbase + row] = s + rb3[0];
  } else if (w == 1 && doAB){
    // cell-relation chain: cr1 -> cr2 -> crF -> Y
    u16* bA = sU + 2 * TBUF;
    u16* bB = sU + 3 * TBUF;
    Frags f = load_afrags_s(sA, 0, lane);
    layer_g(f, pWB + 0 * FCH, crB, bA, LDP, 0, true, lane);          lds_fence();
    f = load_afrags_s(bA, 0, lane);
    layer_g(f, pWB + 1 * FCH, crB + 96, bB, LDP, 0, true, lane);     lds_fence();
    f = load_afrags_s(bB, 0, lane);
    layer_g(f, pWB + 2 * FCH, bY, Y, 96, rbase, false, lane);
  } else if (w == 2 && doAB){
    // digit-relation chain: dr1 -> dr2 -> drF -> Z
    u16* bA = sU + 4 * TBUF;
    u16* bB = sU + 5 * TBUF;
    Frags f = load_afrags_s(sA, 0, lane);
    layer_g(f, pWB + 3 * FCH, drB, bA, LDP, 0, true, lane);          lds_fence();
    f = load_afrags_s(bA, 0, lane);
    layer_g(f, pWB + 4 * FCH, drB + 96, bB, LDP, 0, true, lane);     lds_fence();
    f = load_afrags_s(bB, 0, lane);
    layer_g(f, pWB + 5 * FCH, bZ, Z, 96, rbase, false, lane);
  }
}

// ============================================================================
extern "C" void kernel_launch(void* const* d_in, const int* in_sizes, int n_in,
                              void* d_out, int out_size, void* d_ws, size_t ws_size,
                              hipStream_t stream)
{
  (void)in_sizes; (void)n_in; (void)out_size; (void)ws_size;
  const int*   inputs = (const int*)d_in[0];
  const float* c0     = (const float*)d_in[1];
  const float* eW1  = (const float*)d_in[4];
  const float* eb1  = (const float*)d_in[5];
  const float* eW2  = (const float*)d_in[6];
  const float* eb2  = (const float*)d_in[7];
  const float* crW  = (const float*)d_in[8];
  const float* crB  = (const float*)d_in[9];
  const float* drW  = (const float*)d_in[10];
  const float* drB  = (const float*)d_in[11];
  const float* gmW1 = (const float*)d_in[12];
  const float* gmb1 = (const float*)d_in[13];
  const float* gmW2 = (const float*)d_in[14];
  const float* gmb2 = (const float*)d_in[15];
  const float* Wih  = (const float*)d_in[16];
  const float* Whh  = (const float*)d_in[17];
  const float* bih  = (const float*)d_in[18];
  const float* bhh  = (const float*)d_in[19];
  const float* rW12 = (const float*)d_in[20];
  const float* rb12 = (const float*)d_in[21];
  const float* rW3  = (const float*)d_in[22];
  const float* rb3  = (const float*)d_in[23];

  char* ws = (char*)d_ws;
  float* XgTab = (float*)(ws);
  float* XTab  = (float*)(ws + 4096);
  float* bsx   = (float*)(ws + 6144);            // 384*4 = 1536 B
  float* bY    = (float*)(ws + 7680);            // 96*4
  float* bZ    = (float*)(ws + 8064);            // 96*4, ends 8448
  u16*   pWB   = (u16*)(ws + 8704);              // 20*9216*2 = 368640 B
  u16* h  = (u16*)(ws + 409600);
  u16* B1 = h  + (size_t)MROWS * 96;             // Y
  u16* B2 = B1 + (size_t)MROWS * 96;             // Z
  float* c = (float*)(B2 + (size_t)MROWS * 96);
  u16* Ssum = (u16*)(c + (size_t)MROWS * 96);    // BN*96 bf16
  u16* adjM = Ssum + (size_t)BN * 96;            // 96*96 bf16 (18 KB)
  float* out = (float*)d_out;

  k_prep2<<<11, 256, 0, stream>>>(crW, drW, gmW2, rW12, Whh, pWB);
  k_prepc<<<18, 256, 0, stream>>>(crW, crB, drW, drB, gmW1, pWB, bY, bZ);
  k_prepf<<<36, 256, 0, stream>>>(gmW2, Wih, pWB);
  k_prepadj<<<1, 256, 0, stream>>>(adjM);
  k_tables<<<1, 128, 0, stream>>>(eW1, eb1, eW2, eb2, gmW1, gmb1, bih, bhh,
                                  gmb2, Wih, XTab, XgTab, bsx);
  k_init<<<(MROWS * 12) / 256, 256, 0, stream>>>(inputs, XTab, h);
  k_ab3<<<GRID_TILE, 256, 0, stream>>>(h, B1, B2, pWB, crB, drB, bY, bZ);

  for (int it = 0; it < 4; ++it){
    const float* cin = (it == 0) ? c0 : c;
    k_msg<<<1152 + 486, 256, 0, stream>>>(B2, B1, Ssum, adjM);
    k_fuse16x<<<FUSE_GRID, 256, 0, stream>>>(B1, B2, Ssum, inputs, XgTab, pWB,
                                             gmb2, h, cin, c, bsx, rb12, rW3, rb3,
                                             out + (size_t)it * MROWS,
                                             crB, drB, bY, bZ, (it < 3) ? 1 : 0);
  }
}

// Round 17
// 614.181 us; speedup vs baseline: 1.4331x; 1.0228x over previous
//
#include <hip/hip_runtime.h>
#include <hip/hip_bf16.h>

typedef unsigned short u16;
typedef __bf16 bf16x8 __attribute__((ext_vector_type(8)));   // MFMA A/B operand (4 VGPRs)
typedef float  f32x4  __attribute__((ext_vector_type(4)));   // MFMA C/D operand
typedef u16    u16x8  __attribute__((ext_vector_type(8)));

#define HID   96
#define LDP   104          // padded LDS row stride for activation slices
#define MROWS 93312        // B*N*D
#define BN    10368        // B*N
#define GRID_TILE 1458     // MROWS/64
#define FUSE_GRID 5832     // MROWS/16
#define SGX   100          // f32 LDS stride gate exchange: 4*100 ≡ 16 mod 32 → 2-way (free)
#define PST   97           // padded f32 stride for prep staging (kills 32-way conflicts)
#define TBUF  1664         // u16 elems per 16-row tail buffer (16*LDP)
#define FST   520          // padded u16 frag stride in k_msg LDS (f-step of 3 → bank+12)

// B-fragment-ordered weights: 20 chunks x 18 frags x 512 elems (1KB frags)
// chunk: 0 cr1, 1 cr2, 2 crF=crW2@W1b, 3 dr1, 4 dr2, 5 drF=drW2@W1c,
//        8 gm2a, 10-11 rW12, 12-15 Wf=W2b@Wih^T (gates i,f,g,o), 16-19 Whh
#define FCH 9216           // elems per chunk (18*512)

#define MFMA(a,b,c) __builtin_amdgcn_mfma_f32_16x16x32_bf16((a),(b),(c),0,0,0)

__device__ __forceinline__ float bf2f(u16 x){
  union { float f; unsigned u; } v; v.u = ((unsigned)x) << 16; return v.f;
}
// native cast -> v_cvt_pk_bf16_f32 (RNE, 1 instr / 2 values when paired)
__device__ __forceinline__ u16 f2bf(float f){
  union { __bf16 b; u16 u; } v; v.b = (__bf16)f; return v.u;
}
__device__ __forceinline__ float frcp(float x){ return __builtin_amdgcn_rcpf(x); }
__device__ __forceinline__ float sigf(float x){ return frcp(1.f + __expf(-x)); }
__device__ __forceinline__ float tanhf_(float x){
  float xx = fminf(fmaxf(x, -15.f), 15.f);
  float e = __expf(-2.f * xx);
  return (1.f - e) * frcp(1.f + e);
}
// in-wave LDS write->read ordering (wave-private slices only)
__device__ __forceinline__ void lds_fence(){
  asm volatile("s_waitcnt lgkmcnt(0)" ::: "memory");
}

// ---- fragment loaders -------------------------------------------------------
struct Frags { bf16x8 a0, a1, a2; };

__device__ __forceinline__ Frags load_afrags_g(const u16* __restrict__ A, size_t row0, int lane){
  int t16 = lane & 15, q = lane >> 4;
  const u16* p = A + (row0 + (size_t)t16) * 96 + q * 8;
  Frags f;
  f.a0 = *reinterpret_cast<const bf16x8*>(p);
  f.a1 = *reinterpret_cast<const bf16x8*>(p + 32);
  f.a2 = *reinterpret_cast<const bf16x8*>(p + 64);
  return f;
}
__device__ __forceinline__ Frags load_afrags_s(const u16* sA, int row0, int lane){
  int t16 = lane & 15, q = lane >> 4;
  const u16* p = sA + (row0 + t16) * LDP + q * 8;
  Frags f;
  f.a0 = *reinterpret_cast<const bf16x8*>(p);
  f.a1 = *reinterpret_cast<const bf16x8*>(p + 32);
  f.a2 = *reinterpret_cast<const bf16x8*>(p + 64);
  return f;
}

// ---- one 16x96 layer, weights as global B-frags (L1/L2-resident) ------------
__device__ __forceinline__ void layer_g(Frags f, const u16* __restrict__ wb,
    const float* __restrict__ bias, u16* dst, int dstStride, size_t rowBase,
    bool relu, int lane)
{
  int t16 = lane & 15, q = lane >> 4;
  #pragma unroll
  for (int nt = 0; nt < 6; nt++){
    float b = bias ? bias[nt * 16 + t16] : 0.f;
    f32x4 acc = {b, b, b, b};
    const u16* wp = wb + nt * 1536 + lane * 8;
    acc = MFMA(f.a0, *reinterpret_cast<const bf16x8*>(wp),        acc);
    acc = MFMA(f.a1, *reinterpret_cast<const bf16x8*>(wp + 512),  acc);
    acc = MFMA(f.a2, *reinterpret_cast<const bf16x8*>(wp + 1024), acc);
    #pragma unroll
    for (int j = 0; j < 4; j++){
      float v = acc[j];
      if (relu) v = fmaxf(v, 0.f);
      dst[(rowBase + q * 4 + j) * (size_t)dstStride + nt * 16 + t16] = f2bf(v);
    }
  }
}

// 16-row layer split across 4 waves by col-tile (wave w: nt = w, w+4).
// Cross-wave data: caller must __syncthreads() before reading dst frags.
__device__ __forceinline__ void layer_split(Frags f, const u16* __restrict__ wb,
    const float* __restrict__ bias, u16* dst, bool relu, int lane, int w)
{
  int t16 = lane & 15, q = lane >> 4;
  #pragma unroll
  for (int nt = w; nt < 6; nt += 4){
    float b = bias ? bias[nt * 16 + t16] : 0.f;
    f32x4 acc = {b, b, b, b};
    const u16* wp = wb + nt * 1536 + lane * 8;
    acc = MFMA(f.a0, *reinterpret_cast<const bf16x8*>(wp),        acc);
    acc = MFMA(f.a1, *reinterpret_cast<const bf16x8*>(wp + 512),  acc);
    acc = MFMA(f.a2, *reinterpret_cast<const bf16x8*>(wp + 1024), acc);
    #pragma unroll
    for (int j = 0; j < 4; j++){
      float v = acc[j];
      if (relu) v = fmaxf(v, 0.f);
      dst[(q * 4 + j) * LDP + nt * 16 + t16] = f2bf(v);
    }
  }
}

// 16-row layer split across 2 waves by col-tile (pair pos p in {0,1}:
// nt = p, p+2, p+4). Caller barriers before cross-wave frag reads.
__device__ __forceinline__ void layer_split2(Frags f, const u16* __restrict__ wb,
    const float* __restrict__ bias, u16* dst, bool relu, int lane, int p)
{
  int t16 = lane & 15, q = lane >> 4;
  #pragma unroll
  for (int nt = p; nt < 6; nt += 2){
    float b = bias ? bias[nt * 16 + t16] : 0.f;
    f32x4 acc = {b, b, b, b};
    const u16* wp = wb + nt * 1536 + lane * 8;
    acc = MFMA(f.a0, *reinterpret_cast<const bf16x8*>(wp),        acc);
    acc = MFMA(f.a1, *reinterpret_cast<const bf16x8*>(wp + 512),  acc);
    acc = MFMA(f.a2, *reinterpret_cast<const bf16x8*>(wp + 1024), acc);
    #pragma unroll
    for (int j = 0; j < 4; j++){
      float v = acc[j];
      if (relu) v = fmaxf(v, 0.f);
      dst[(q * 4 + j) * LDP + nt * 16 + t16] = f2bf(v);
    }
  }
}

// same, but writes to global rows [rbase, rbase+16), stride 96
__device__ __forceinline__ void layer_split2_gout(Frags f, const u16* __restrict__ wb,
    const float* __restrict__ bias, u16* gdst, size_t rbase, bool relu, int lane, int p)
{
  int t16 = lane & 15, q = lane >> 4;
  #pragma unroll
  for (int nt = p; nt < 6; nt += 2){
    float b = bias ? bias[nt * 16 + t16] : 0.f;
    f32x4 acc = {b, b, b, b};
    const u16* wp = wb + nt * 1536 + lane * 8;
    acc = MFMA(f.a0, *reinterpret_cast<const bf16x8*>(wp),        acc);
    acc = MFMA(f.a1, *reinterpret_cast<const bf16x8*>(wp + 512),  acc);
    acc = MFMA(f.a2, *reinterpret_cast<const bf16x8*>(wp + 1024), acc);
    #pragma unroll
    for (int j = 0; j < 4; j++){
      float v = acc[j];
      if (relu) v = fmaxf(v, 0.f);
      gdst[(rbase + q * 4 + j) * 96 + nt * 16 + t16] = f2bf(v);
    }
  }
}

// 6 col-tiles accumulated into acc[0..6), weights from global frags
__device__ __forceinline__ void mfma6_g(f32x4* acc, Frags f,
    const u16* __restrict__ wb, int lane)
{
  #pragma unroll
  for (int jt = 0; jt < 6; jt++){
    const u16* wp = wb + jt * 1536 + lane * 8;
    acc[jt] = MFMA(f.a0, *reinterpret_cast<const bf16x8*>(wp),        acc[jt]);
    acc[jt] = MFMA(f.a1, *reinterpret_cast<const bf16x8*>(wp + 512),  acc[jt]);
    acc[jt] = MFMA(f.a2, *reinterpret_cast<const bf16x8*>(wp + 1024), acc[jt]);
  }
}

// ============================================================================
// K_prep2: f32 weights -> bf16 B-fragment layout (direct chunks).
// frag elem (f, l, j): nt=f/3, kc=f%3, n=nt*16+(l&15), k=(l>>4)*8+kc*32+j
__global__ __launch_bounds__(256) void k_prep2(const float* __restrict__ crW,
    const float* __restrict__ drW, const float* __restrict__ gmW2,
    const float* __restrict__ rW12, const float* __restrict__ Whh,
    u16* __restrict__ pWB)
{
  int b = blockIdx.x, tid = threadIdx.x;
  if (b < 7){
    const float* src; int ch;                   // row-major [k][n]
    if      (b == 0){ src = crW;          ch = 0;  }
    else if (b == 1){ src = crW  + 9216;  ch = 1;  }
    else if (b == 2){ src = drW;          ch = 3;  }
    else if (b == 3){ src = drW  + 9216;  ch = 4;  }
    else if (b == 4){ src = gmW2;         ch = 8;  }
    else if (b == 5){ src = rW12;         ch = 10; }
    else            { src = rW12 + 9216;  ch = 11; }
    u16* dst = pWB + ch * FCH;
    #pragma unroll
    for (int i = 0; i < 36; i++){
      int idx = tid + i * 256;
      int f = idx >> 9, rem = idx & 511, l = rem >> 3, j = rem & 7;
      int nt = f / 3, kc = f - nt * 3;
      int n = nt * 16 + (l & 15);
      int k = ((l >> 4) << 3) + kc * 32 + j;
      dst[idx] = f2bf(src[k * 96 + n]);
    }
  } else {
    int bb = b - 7;                             // 0..3 Whh gate chunks
    u16* dst = pWB + (16 + bb) * FCH;
    const float* src = Whh + bb * 9216;         // [n][k]
    #pragma unroll
    for (int i = 0; i < 36; i++){
      int idx = tid + i * 256;
      int f = idx >> 9, rem = idx & 511, l = rem >> 3, j = rem & 7;
      int nt = f / 3, kc = f - nt * 3;
      int n = nt * 16 + (l & 15);
      int k = ((l >> 4) << 3) + kc * 32 + j;
      dst[idx] = f2bf(src[n * 96 + k]);
    }
  }
}

// K_prepadj: static Sudoku adjacency as 96x96 bf16 row-major (0/1 exact).
// Rows/cols >= 81 are zero (kills pad garbage in the MFMA msg kernel).
__global__ __launch_bounds__(256) void k_prepadj(u16* __restrict__ adjM)
{
  int tid = threadIdx.x;
  for (int i = tid; i < 9216; i += 256){
    int m = i / 96, n = i - (i / 96) * 96;
    float v = 0.f;
    if (m < 81 && n < 81 && m != n){
      int rm = m / 9, cm = m - rm * 9;
      int rn = n / 9, cn = n - rn * 9;
      if (rm == rn || cm == cn || ((rm / 3 == rn / 3) && (cm / 3 == cn / 3)))
        v = 1.f;
    }
    adjM[i] = f2bf(v);
  }
}

// K_prepc: folded cell/digit output weights.
// g=0: chunk2 = crW[2] @ W1b, bY = crb[2] @ W1b  (W1b = gmW1 rows 96..191)
// g=1: chunk5 = drW[2] @ W1c, bZ = drb[2] @ W1c  (W1c = gmW1 rows 192..287)
__global__ __launch_bounds__(256) void k_prepc(const float* __restrict__ crW,
    const float* __restrict__ crB, const float* __restrict__ drW,
    const float* __restrict__ drB, const float* __restrict__ gmW1,
    u16* __restrict__ pWB, float* __restrict__ bY, float* __restrict__ bZ)
{
  __shared__ float sM[96 * PST];                // left [k][j]
  __shared__ float sW[96 * PST];                // right [j][n]
  int b = blockIdx.x, g = b / 9, seg = b - g * 9, tid = threadIdx.x;
  const float* L = (g == 0 ? crW : drW) + 2 * 9216;
  const float* R = gmW1 + (g == 0 ? 9216 : 18432);
  for (int i = tid; i < 9216; i += 256){
    int r = i / 96, cc = i - r * 96;
    sM[r * PST + cc] = L[i];
    sW[r * PST + cc] = R[i];
  }
  __syncthreads();
  if (seg == 0){
    const float* bv = (g == 0 ? crB : drB) + 192;
    float* bo = (g == 0 ? bY : bZ);
    for (int n = tid; n < 96; n += 256){
      float a = 0.f;
      for (int j = 0; j < 96; j++) a += bv[j] * sW[j * PST + n];
      bo[n] = a;
    }
  }
  u16* dst = pWB + (g == 0 ? 2 : 5) * FCH;
  #pragma unroll
  for (int i = 0; i < 4; i++){
    int idx = seg * 1024 + tid + i * 256;
    int f = idx >> 9, rem = idx & 511, l = rem >> 3, j = rem & 7;
    int nt = f / 3, kc = f - nt * 3;
    int n = nt * 16 + (l & 15);
    int k = ((l >> 4) << 3) + kc * 32 + j;
    float a = 0.f;
    #pragma unroll 4
    for (int jj = 0; jj < 96; jj++) a += sM[k * PST + jj] * sW[jj * PST + n];
    dst[idx] = f2bf(a);
  }
}

// K_prepf: fused x-path weight Wf = W2b @ Wih^T -> frag chunks 12-15.
__global__ __launch_bounds__(256) void k_prepf(const float* __restrict__ gmW2,
    const float* __restrict__ Wih, u16* __restrict__ pWB)
{
  __shared__ float sW[96 * PST];                // W2b staged, padded stride
  int b = blockIdx.x, g = b / 9, seg = b - g * 9, tid = threadIdx.x;
  for (int i = tid; i < 9216; i += 256){
    int r = i / 96, cc = i - r * 96;
    sW[r * PST + cc] = gmW2[9216 + i];
  }
  __syncthreads();
  u16* dst = pWB + (12 + g) * FCH;
  #pragma unroll
  for (int i = 0; i < 4; i++){
    int idx = seg * 1024 + tid + i * 256;
    int f = idx >> 9, rem = idx & 511, l = rem >> 3, j = rem & 7;
    int nt = f / 3, kc = f - nt * 3;
    int n = nt * 16 + (l & 15);
    int k = ((l >> 4) << 3) + kc * 32 + j;
    const float* wr = Wih + (g * 96 + n) * 96;
    float a = 0.f;
    #pragma unroll 4
    for (int jj = 0; jj < 96; jj++) a += sW[k * PST + jj] * wr[jj];
    dst[idx] = f2bf(a);
  }
}

// K0: tables (f32) + fused LSTM bias bsx = bih + bhh + b2b @ Wih^T
__global__ void k_tables(const float* __restrict__ eW1, const float* __restrict__ eb1,
                         const float* __restrict__ eW2, const float* __restrict__ eb2,
                         const float* __restrict__ gmW1, const float* __restrict__ gmb1,
                         const float* __restrict__ bih, const float* __restrict__ bhh,
                         const float* __restrict__ gmb2, const float* __restrict__ Wih,
                         float* __restrict__ XTab, float* __restrict__ XgTab,
                         float* __restrict__ bsx)
{
  __shared__ float sX[3][96];
  int j = threadIdx.x;
  for (int n = j; n < 384; n += 128){
    float acc = bih[n] + bhh[n];
    const float* wr = Wih + n * 96;
    for (int jj = 0; jj < 96; jj++) acc += gmb2[96 + jj] * wr[jj];
    bsx[n] = acc;
  }
  if (j < 96){
    for (int ch = 0; ch < 3; ch++){
      float acc = eb2[j];
      for (int e = 0; e < 16; e++){
        float hv = fmaxf(eW1[ch * 16 + e] + eb1[e], 0.f);
        acc += hv * eW2[e * 96 + j];
      }
      sX[ch][j] = acc;
      XTab[ch * 96 + j] = acc;
    }
  }
  __syncthreads();
  if (j < 96){
    for (int ch = 0; ch < 3; ch++){
      float acc = gmb1[j];
      for (int k = 0; k < 96; k++) acc += sX[ch][k] * gmW1[k * 96 + j];
      XgTab[ch * 96 + j] = acc;
    }
  }
}

// K_init: h only (c0 read directly on iter 0)
__global__ __launch_bounds__(256) void k_init(const int* __restrict__ inputs,
    const float* __restrict__ XTab, u16* __restrict__ h)
{
  int idx = blockIdx.x * 256 + threadIdx.x;     // exactly MROWS*12
  int m = idx / 12, h8 = idx - m * 12;
  int bn = m / 9, d = m - bn * 9;
  int inp = inputs[bn];
  int ch = (inp == 0) ? 0 : ((inp == d + 1) ? 1 : 2);
  const float* xt = XTab + ch * 96 + h8 * 8;
  u16* hp = h + (size_t)m * 96 + h8 * 8;
  #pragma unroll
  for (int e = 0; e < 8; e++) hp[e] = f2bf(xt[e]);
}

// K_AB3: h -> cr1,cr2,crF = Y;  h -> dr1,dr2,drF = Z. 6 layers, barrier-free.
// Used once before the loop; later iterations produce Y/Z inside k_fuse16x.
__global__ __launch_bounds__(256) void k_ab3(const u16* __restrict__ h,
    u16* __restrict__ Y, u16* __restrict__ Z,
    const u16* __restrict__ pWB, const float* __restrict__ crB,
    const float* __restrict__ drB, const float* __restrict__ bY,
    const float* __restrict__ bZ)
{
  __shared__ u16 sA[64 * LDP];                  // wave-private 16-row slices
  const int tid = threadIdx.x, lane = tid & 63, wave = tid >> 6;
  const int wrow = wave * 16;
  const size_t rbase = (size_t)blockIdx.x * 64;

  Frags hf = load_afrags_g(h, rbase + wrow, lane);

  layer_g(hf, pWB, crB, sA, LDP, wrow, true, lane);                  lds_fence();
  Frags f = load_afrags_s(sA, wrow, lane);
  layer_g(f, pWB + 1 * FCH, crB + 96, sA, LDP, wrow, true, lane);    lds_fence();
  f = load_afrags_s(sA, wrow, lane);
  layer_g(f, pWB + 2 * FCH, bY, Y, 96, rbase + wrow, false, lane);
  lds_fence();

  layer_g(hf, pWB + 3 * FCH, drB, sA, LDP, wrow, true, lane);        lds_fence();
  f = load_afrags_s(sA, wrow, lane);
  layer_g(f, pWB + 4 * FCH, drB + 96, sA, LDP, wrow, true, lane);    lds_fence();
  f = load_afrags_s(sA, wrow, lane);
  layer_g(f, pWB + 5 * FCH, bZ, Z, 96, rbase + wrow, false, lane);
}

// K_MSG: digit message via MFMA (blocks 0..1151: Z[b,:,d,:] = adj @ Z[b,:,d,:],
// in-place, staged to LDS in B-frag layout with PADDED frag stride FST --
// the 12 lanes sharing n land on 6 distinct banks instead of 1) + scell
// (blocks 1152..1637, Y -> Ssum). adjM = static 96x96 bf16 adjacency.
__global__ __launch_bounds__(256) void k_msg(u16* __restrict__ Z,
    const u16* __restrict__ Y, u16* __restrict__ Ssum,
    const u16* __restrict__ adjM)
{
  __shared__ u16 sF[18 * FST];                  // Z-slice B-frags (18.7 KB)
  const int tid = threadIdx.x;
  if (blockIdx.x >= 1152){
    // ---- scell part: Ssum[bn,:] = sum_d Y[bn,d,:] ----
    int idx = (blockIdx.x - 1152) * 256 + tid;  // exactly BN*12
    int bn = idx / 12, h8 = idx - bn * 12;
    const u16* base = Y + (size_t)bn * 864 + h8 * 8;
    float s[8];
    #pragma unroll
    for (int e = 0; e < 8; e++) s[e] = 0.f;
    #pragma unroll
    for (int d = 0; d < 9; d++){
      u16x8 v = *reinterpret_cast<const u16x8*>(base + d * 96);
      #pragma unroll
      for (int e = 0; e < 8; e++) s[e] += bf2f(v[e]);
    }
    u16x8 o;
    #pragma unroll
    for (int e = 0; e < 8; e++) o[e] = f2bf(s[e]);
    *reinterpret_cast<u16x8*>(Ssum + (size_t)bn * 96 + h8 * 8) = o;
    return;
  }
  // ---- msgdigit: OUT[m][c] = sum_n adj[m][n] * Z[n][c], MFMA 16x16x32 ----
  const int b = blockIdx.x / 9, d = blockIdx.x - b * 9;
  const size_t base = ((size_t)b * 729 + d) * 96;
  // stage Z-slice (rows 0..80, zeros 81..95) into padded B-frag layout:
  // elem Z[n][c] -> frag f=(c>>4)*3+(n>>5) at offset l*8+j,
  // l=((n>>3)&3)*16+(c&15), j=n&7
  for (int i = tid; i < 1152; i += 256){        // 96 nodes x 12 k8
    int n = i / 12, k8 = i - (i / 12) * 12;
    u16x8 v;
    if (n < 81){
      v = *reinterpret_cast<const u16x8*>(Z + base + (size_t)n * 864 + k8 * 8);
    } else {
      for (int e = 0; e < 8; e++) v[e] = 0;
    }
    int f = (k8 >> 1) * 3 + (n >> 5);
    int lbase = ((n >> 3) & 3) * 16 + (k8 & 1) * 8;
    u16* p = sF + f * FST + lbase * 8 + (n & 7);
    #pragma unroll
    for (int e = 0; e < 8; e++) p[e * 8] = v[e];
  }
  __syncthreads();
  const int lane = tid & 63, w = tid >> 6;
  const int t16 = lane & 15, q = lane >> 4;
  #pragma unroll
  for (int ti = 0; ti < 9; ti++){               // 36 output tiles / 4 waves
    int t = w + ti * 4;
    int mt = t / 6, nt = t - mt * 6;
    Frags fa = load_afrags_g(adjM, mt * 16, lane);   // static A (L1-hot)
    f32x4 acc = {0.f, 0.f, 0.f, 0.f};
    const u16* bp = sF + nt * 3 * FST + lane * 8;
    acc = MFMA(fa.a0, *reinterpret_cast<const bf16x8*>(bp),           acc);
    acc = MFMA(fa.a1, *reinterpret_cast<const bf16x8*>(bp + FST),     acc);
    acc = MFMA(fa.a2, *reinterpret_cast<const bf16x8*>(bp + 2 * FST), acc);
    int c = nt * 16 + t16;
    #pragma unroll
    for (int jr = 0; jr < 4; jr++){
      int m = mt * 16 + q * 4 + jr;
      if (m < 81) Z[base + (size_t)m * 864 + c] = f2bf(acc[jr]);
    }
  }
}

// ============================================================================
// K_FUSE16X: 16-row blocks; combine -> gm2a -> LSTM -> BALANCED tail.
// Tail: cr split over {w0,w1}, dr over {w2,w3} (3 col-tiles/wave), then
// readout r1/r2 split 4-way. Critical path 54 -> ~39 MFMA-layer units and
// no idle wave (was: w3 idle for the whole tail). 4 uniform barriers.
// launch_bounds(256,4): the PROVEN config (VGPR 64, no spills).
__global__ __launch_bounds__(256, 4) void k_fuse16x(u16* Y, u16* Z,
    const u16* __restrict__ Ssum,
    const int* __restrict__ inputs, const float* __restrict__ XgTab,
    const u16* __restrict__ pWB, const float* __restrict__ gmb2,
    u16* h, const float* cin, float* cout,
    const float* __restrict__ bsx, const float* __restrict__ rb12,
    const float* __restrict__ rW3, const float* __restrict__ rb3,
    float* __restrict__ out, const float* __restrict__ crB,
    const float* __restrict__ drB, const float* __restrict__ bY,
    const float* __restrict__ bZ, int doAB)
{
  __shared__ u16 sA[16 * LDP];                  // g1 / h_new (3.3 KB)
  __shared__ u16 sU[6 * TBUF];                  // union scratch (19.97 KB)
  u16*   sB   = sU;                             // A1 (P2-P3)
  float* sGhF = reinterpret_cast<float*>(sU + TBUF);  // gates [4][8][SGX] (P4)
  const int tid = threadIdx.x, lane = tid & 63, w = tid >> 6;
  const int t16 = lane & 15, q = lane >> 4;
  const size_t rbase = (size_t)blockIdx.x * 16;

  // ---- EARLY: issue HBM reads consumed in later phases ----
  float cpre[6];
  #pragma unroll
  for (int e = 0; e < 6; e++){
    int idx = e * 256 + tid;
    int r = idx / 96, col = idx - r * 96;
    cpre[e] = cin[(rbase + r) * 96 + col];
  }
  Frags fh = load_afrags_g(h, rbase, lane);     // old h (own rows)

  // ---- P1: combine g1 = relu(Xg + (Ssum - Y) + Zd) -> sA ----
  if (tid < 192){
    int rl = tid / 12, kc = tid - rl * 12;
    int m = (int)rbase + rl;
    int bn = m / 9, d = m - bn * 9;
    int inp = inputs[bn];
    int ch = (inp == 0) ? 0 : ((inp == d + 1) ? 1 : 2);
    const float* xg = XgTab + ch * 96 + kc * 8;
    u16x8 vy = *reinterpret_cast<const u16x8*>(Y    + (size_t)m * 96 + kc * 8);
    u16x8 vz = *reinterpret_cast<const u16x8*>(Z    + (size_t)m * 96 + kc * 8);
    u16x8 vs = *reinterpret_cast<const u16x8*>(Ssum + (size_t)bn * 96 + kc * 8);
    u16x8 o;
    #pragma unroll
    for (int e = 0; e < 8; e++)
      o[e] = f2bf(fmaxf(xg[e] + bf2f(vs[e]) - bf2f(vy[e]) + bf2f(vz[e]), 0.f));
    *reinterpret_cast<u16x8*>(sA + rl * LDP + kc * 8) = o;
  }
  __syncthreads();

  // ---- P2: gm2a (wave-split col-tiles) -> sB (A1) ----
  {
    Frags f = load_afrags_s(sA, 0, lane);
    layer_split(f, pWB + 8 * FCH, gmb2, sB, true, lane, w);
  }
  __syncthreads();

  // ---- P3: LSTM gates, wave w = gate w ----
  f32x4 acc[6];
  #pragma unroll
  for (int nt = 0; nt < 6; nt++){
    float b = bsx[w * 96 + nt * 16 + t16];
    f32x4 a = {b, b, b, b};
    acc[nt] = a;
  }
  {
    Frags fa = load_afrags_s(sB, 0, lane);
    mfma6_g(acc, fa, pWB + (12 + w) * FCH, lane);   // x-path: A1 @ Wf_w^T
    mfma6_g(acc, fh, pWB + (16 + w) * FCH, lane);   // h-path: h  @ Whh_w^T
  }

  // ---- P4a: gate half rows 0..7 (lanes q<2) -> epilogue ----
  if (q < 2){
    #pragma unroll
    for (int nt = 0; nt < 6; nt++)
      #pragma unroll
      for (int j = 0; j < 4; j++)
        sGhF[(w * 8 + q * 4 + j) * SGX + nt * 16 + t16] = acc[nt][j];
  }
  __syncthreads();
  #pragma unroll
  for (int e = 0; e < 3; e++){
    int idx = e * 256 + tid;                    // 0..767 -> rows 0..7
    int r = idx / 96, col = idx - r * 96;
    float iv = sGhF[(0 * 8 + r) * SGX + col];
    float fv = sGhF[(1 * 8 + r) * SGX + col];
    float gv = sGhF[(2 * 8 + r) * SGX + col];
    float ov = sGhF[(3 * 8 + r) * SGX + col];
    size_t m = rbase + r;
    float cn = sigf(fv) * cpre[e] + sigf(iv) * tanhf_(gv);
    float hn = sigf(ov) * tanhf_(cn);
    cout[m * 96 + col] = cn;
    u16 hb = f2bf(hn);
    h[m * 96 + col] = hb;
    sA[r * LDP + col] = hb;
  }
  __syncthreads();

  // ---- P4b: gate half rows 8..15 (lanes q>=2) -> epilogue ----
  if (q >= 2){
    #pragma unroll
    for (int nt = 0; nt < 6; nt++)
      #pragma unroll
      for (int j = 0; j < 4; j++)
        sGhF[(w * 8 + (q - 2) * 4 + j) * SGX + nt * 16 + t16] = acc[nt][j];
  }
  __syncthreads();
  #pragma unroll
  for (int e = 0; e < 3; e++){
    int idx = (e + 3) * 256 + tid;              // 768..1535 -> rows 8..15
    int r = idx / 96, col = idx - r * 96;
    float iv = sGhF[(0 * 8 + r - 8) * SGX + col];
    float fv = sGhF[(1 * 8 + r - 8) * SGX + col];
    float gv = sGhF[(2 * 8 + r - 8) * SGX + col];
    float ov = sGhF[(3 * 8 + r - 8) * SGX + col];
    size_t m = rbase + r;
    float cn = sigf(fv) * cpre[e + 3] + sigf(iv) * tanhf_(gv);
    float hn = sigf(ov) * tanhf_(cn);
    cout[m * 96 + col] = cn;
    u16 hb = f2bf(hn);
    h[m * 96 + col] = hb;
    sA[r * LDP + col] = hb;
  }
  __syncthreads();                               // sA = h_new, visible to all

  // ---- BALANCED TAIL (sU fully dead -> 6 tail buffers) ----
  u16* bCr0 = sU + 0 * TBUF;
  u16* bCr1 = sU + 1 * TBUF;
  u16* bDr0 = sU + 2 * TBUF;
  u16* bDr1 = sU + 3 * TBUF;
  u16* bR0  = sU + 4 * TBUF;
  u16* bR1  = sU + 5 * TBUF;

  // T1: cr1 on {w0,w1}, dr1 on {w2,w3} (3 col-tiles per wave)
  if (doAB){
    Frags f = load_afrags_s(sA, 0, lane);
    if (w < 2) layer_split2(f, pWB + 0 * FCH, crB, bCr0, true, lane, w);
    else       layer_split2(f, pWB + 3 * FCH, drB, bDr0, true, lane, w - 2);
  }
  __syncthreads();
  // T2: cr2 / dr2
  if (doAB){
    if (w < 2){
      Frags f = load_afrags_s(bCr0, 0, lane);
      layer_split2(f, pWB + 1 * FCH, crB + 96, bCr1, true, lane, w);
    } else {
      Frags f = load_afrags_s(bDr0, 0, lane);
      layer_split2(f, pWB + 4 * FCH, drB + 96, bDr1, true, lane, w - 2);
    }
  }
  __syncthreads();
  // T3: crF -> Y / drF -> Z (global; no barrier needed before R1, which
  // reads only sA and writes bR0)
  if (doAB){
    if (w < 2){
      Frags f = load_afrags_s(bCr1, 0, lane);
      layer_split2_gout(f, pWB + 2 * FCH, bY, Y, rbase, false, lane, w);
    } else {
      Frags f = load_afrags_s(bDr1, 0, lane);
      layer_split2_gout(f, pWB + 5 * FCH, bZ, Z, rbase, false, lane, w - 2);
    }
  }
  // R1: readout layer 1, all 4 waves (4-way col split)
  {
    Frags f = load_afrags_s(sA, 0, lane);
    layer_split(f, pWB + 10 * FCH, rb12, bR0, true, lane, w);
  }
  __syncthreads();
  // R2: readout layer 2, all 4 waves
  {
    Frags f = load_afrags_s(bR0, 0, lane);
    layer_split(f, pWB + 11 * FCH, rb12 + 96, bR1, true, lane, w);
  }
  __syncthreads();
  // dot: wave 0
  if (w == 0){
    int row = lane >> 2, part = lane & 3;
    float s = 0.f;
    const u16* rp = bR1 + row * LDP + part * 24;
    #pragma unroll
    for (int k = 0; k < 24; k++) s += bf2f(rp[k]) * rW3[part * 24 + k];
    s += __shfl_xor(s, 1);
    s += __shfl_xor(s, 2);
    if (part == 0) out[rbase + row] = s + rb3[0];
  }
}

// ============================================================================
extern "C" void kernel_launch(void* const* d_in, const int* in_sizes, int n_in,
                              void* d_out, int out_size, void* d_ws, size_t ws_size,
                              hipStream_t stream)
{
  (void)in_sizes; (void)n_in; (void)out_size; (void)ws_size;
  const int*   inputs = (const int*)d_in[0];
  const float* c0     = (const float*)d_in[1];
  const float* eW1  = (const float*)d_in[4];
  const float* eb1  = (const float*)d_in[5];
  const float* eW2  = (const float*)d_in[6];
  const float* eb2  = (const float*)d_in[7];
  const float* crW  = (const float*)d_in[8];
  const float* crB  = (const float*)d_in[9];
  const float* drW  = (const float*)d_in[10];
  const float* drB  = (const float*)d_in[11];
  const float* gmW1 = (const float*)d_in[12];
  const float* gmb1 = (const float*)d_in[13];
  const float* gmW2 = (const float*)d_in[14];
  const float* gmb2 = (const float*)d_in[15];
  const float* Wih  = (const float*)d_in[16];
  const float* Whh  = (const float*)d_in[17];
  const float* bih  = (const float*)d_in[18];
  const float* bhh  = (const float*)d_in[19];
  const float* rW12 = (const float*)d_in[20];
  const float* rb12 = (const float*)d_in[21];
  const float* rW3  = (const float*)d_in[22];
  const float* rb3  = (const float*)d_in[23];

  char* ws = (char*)d_ws;
  float* XgTab = (float*)(ws);
  float* XTab  = (float*)(ws + 4096);
  float* bsx   = (float*)(ws + 6144);            // 384*4 = 1536 B
  float* bY    = (float*)(ws + 7680);            // 96*4
  float* bZ    = (float*)(ws + 8064);            // 96*4, ends 8448
  u16*   pWB   = (u16*)(ws + 8704);              // 20*9216*2 = 368640 B
  u16* h  = (u16*)(ws + 409600);
  u16* B1 = h  + (size_t)MROWS * 96;             // Y
  u16* B2 = B1 + (size_t)MROWS * 96;             // Z
  float* c = (float*)(B2 + (size_t)MROWS * 96);
  u16* Ssum = (u16*)(c + (size_t)MROWS * 96);    // BN*96 bf16
  u16* adjM = Ssum + (size_t)BN * 96;            // 96*96 bf16 (18 KB)
  float* out = (float*)d_out;

  k_prep2<<<11, 256, 0, stream>>>(crW, drW, gmW2, rW12, Whh, pWB);
  k_prepc<<<18, 256, 0, stream>>>(crW, crB, drW, drB, gmW1, pWB, bY, bZ);
  k_prepf<<<36, 256, 0, stream>>>(gmW2, Wih, pWB);
  k_prepadj<<<1, 256, 0, stream>>>(adjM);
  k_tables<<<1, 128, 0, stream>>>(eW1, eb1, eW2, eb2, gmW1, gmb1, bih, bhh,
                                  gmb2, Wih, XTab, XgTab, bsx);
  k_init<<<(MROWS * 12) / 256, 256, 0, stream>>>(inputs, XTab, h);
  k_ab3<<<GRID_TILE, 256, 0, stream>>>(h, B1, B2, pWB, crB, drB, bY, bZ);

  for (int it = 0; it < 4; ++it){
    const float* cin = (it == 0) ? c0 : c;
    k_msg<<<1152 + 486, 256, 0, stream>>>(B2, B1, Ssum, adjM);
    k_fuse16x<<<FUSE_GRID, 256, 0, stream>>>(B1, B2, Ssum, inputs, XgTab, pWB,
                                             gmb2, h, cin, c, bsx, rb12, rW3, rb3,
                                             out + (size_t)it * MROWS,
                                             crB, drB, bY, bZ, (it < 3) ? 1 : 0);
  }
}